// Round 2
// baseline (351.824 us; speedup 1.0000x reference)
//
#include <hip/hip_runtime.h>
#include <math.h>

#define DCH 384
#define NH 12
#define CH 32
#define SS 128
#define LL 256
#define NPOS 32768        // SS*LL
#define THREE_D 1152

typedef _Float16 f16_t;
typedef _Float16 f16x4 __attribute__((ext_vector_type(4)));
typedef _Float16 f16x8 __attribute__((ext_vector_type(8)));
typedef float f32x4 __attribute__((ext_vector_type(4)));

// async global->LDS, 16B per lane.
// SOURCE: per-lane global address (must include lane term yourself!)
// DEST:   wave-uniform LDS base; HW adds lane*16.
#define GLD16(gptr, lptr) __builtin_amdgcn_global_load_lds( \
    (const __attribute__((address_space(1))) unsigned int*)(gptr), \
    (__attribute__((address_space(3))) unsigned int*)(lptr), 16, 0, 0)

// wave-local LDS drain: same-wave cross-lane ds_write -> ds_read ordering.
#define WAVE_LDS_FENCE() __asm__ volatile("s_waitcnt lgkmcnt(0)" ::: "memory")

// ---------------------------------------------------------------------------
// fp32 -> fp16 elementwise (weights, layout preserved). n4 = count/4.
// ---------------------------------------------------------------------------
__global__ __launch_bounds__(256) void conv_w(const float* __restrict__ in,
                                              f16_t* __restrict__ out, int n4) {
    int i = blockIdx.x * 256 + threadIdx.x;
    if (i < n4) {
        float4 v = ((const float4*)in)[i];
        unsigned short u0 = __builtin_bit_cast(unsigned short, (f16_t)v.x);
        unsigned short u1 = __builtin_bit_cast(unsigned short, (f16_t)v.y);
        unsigned short u2 = __builtin_bit_cast(unsigned short, (f16_t)v.z);
        unsigned short u3 = __builtin_bit_cast(unsigned short, (f16_t)v.w);
        uint2 r;
        r.x = (unsigned)u0 | ((unsigned)u1 << 16);
        r.y = (unsigned)u2 | ((unsigned)u3 << 16);
        ((uint2*)out)[i] = r;
    }
}

// ---------------------------------------------------------------------------
// fp32 [DCH][NPOS] -> fp16 [NPOS][DCH]  (transpose + convert, 64x64 tiles)
// ---------------------------------------------------------------------------
__global__ __launch_bounds__(256) void conv_xT(const float* __restrict__ in,
                                               f16_t* __restrict__ outp) {
    __shared__ float tile[64][65];
    const int p0 = blockIdx.x * 64;
    const int k0 = blockIdx.y * 64;
    const int tx = threadIdx.x & 63, ty = threadIdx.x >> 6;  // ty 0..3
#pragma unroll
    for (int i = 0; i < 16; ++i)
        tile[ty * 16 + i][tx] = in[(size_t)(k0 + ty * 16 + i) * NPOS + p0 + tx];
    __syncthreads();
    const int pr = threadIdx.x >> 2;   // 0..63 output row (p)
    const int cg = threadIdx.x & 3;    // 16-col group (k)
    union { uint4 v[2]; unsigned int u[8]; } res;
#pragma unroll
    for (int j = 0; j < 8; ++j) {
        unsigned short lo = __builtin_bit_cast(unsigned short, (f16_t)tile[cg * 16 + 2 * j][pr]);
        unsigned short hi = __builtin_bit_cast(unsigned short, (f16_t)tile[cg * 16 + 2 * j + 1][pr]);
        res.u[j] = (unsigned)lo | ((unsigned)hi << 16);
    }
    uint4* dst = (uint4*)&outp[(size_t)(p0 + pr) * DCH + k0 + cg * 16];
    dst[0] = res.v[0];
    dst[1] = res.v[1];
}

// ---------------------------------------------------------------------------
// fp16 MFMA GEMM producing attention-friendly fp16 outputs:
//   q,k -> Yq/Yk [NH][NPOS][CH]   (p-major rows of 32 ch: direct MFMA frags)
//   v   -> Yv [DCH][NPOS]         (c-major: V^T A-frag rows)
//
// R1: 2-phase double-buffered prefetch + bijective XCD swizzle (FETCH 115->18MB).
// R2: T2 k-group XOR swizzle kg' = kg ^ ((row>>1)&3) on sha/shb.
//     Rule #21: LDS dest stays linear (global_load_lds), global SOURCE carries
//     the inverse permutation (XOR = involution), ds_read applies same XOR.
//     Kills the 4x/read bank serialization (row stride 64B put 16 lanes on 2
//     bank groups; now 2 dwords/bank = HW minimum).
// ---------------------------------------------------------------------------
__global__ __launch_bounds__(256) void qkv_gemm_f16(
        const f16_t* __restrict__ Wh,    // [THREE_D][DCH]
        const float* __restrict__ bias,  // [THREE_D]
        const f16_t* __restrict__ Xp,    // [NPOS][DCH]
        f16_t* __restrict__ Yq, f16_t* __restrict__ Yk, f16_t* __restrict__ Yv)
{
    __shared__ f16_t sha[2][128 * 32];  // [buf][o_local][k-swz] 2x8 KB
    __shared__ f16_t shb[2][128 * 32];  // [buf][p_local][k-swz] 2x8 KB
    const int tid  = threadIdx.x;
    const int lane = tid & 63;
    const int wave = tid >> 6;

    // Bijective XCD swizzle: nwg = 9*256 = 2304 = 8 * 288.
    const int hwid = blockIdx.y * 9 + blockIdx.x;      // x fastest in dispatch
    const int nid  = (hwid & 7) * 288 + (hwid >> 3);
    const int ot   = nid % 9;                           // 0..8
    const int pt   = nid / 9;                           // 0..255
    const int o0 = ot * 128;
    const int p0 = pt * 128;
    const int wr = wave >> 1, wc = wave & 1;   // 2x2 wave grid

    f32x4 acc[4][4] = {};

    // staging: lane covers (row = c>>2, kg_slot = c&3); source k-group is
    // pre-swizzled so that LDS slot (row, kg_slot) holds data kg_slot^key(row).
    const int c0 = wave * 128 + lane;
    const int c1 = c0 + 64;
    const int r0 = c0 >> 2, r1 = c1 >> 2;
    const int kg0 = (c0 & 3) ^ ((r0 >> 1) & 3);
    const int kg1 = (c1 & 3) ^ ((r1 >> 1) & 3);
    const f16_t* ga0 = Wh + (size_t)(o0 + r0) * DCH + kg0 * 8;
    const f16_t* ga1 = Wh + (size_t)(o0 + r1) * DCH + kg1 * 8;
    const f16_t* gb0 = Xp + (size_t)(p0 + r0) * DCH + kg0 * 8;
    const f16_t* gb1 = Xp + (size_t)(p0 + r1) * DCH + kg1 * 8;
    const int lofA0 = (wave * 128) * 8;        // f16 units, wave-uniform base
    const int lofA1 = (wave * 128 + 64) * 8;

    const int mrow = lane & 15;
    const int kgq  = lane >> 4;                       // fragment k-group 0..3
    const int kgr8 = (kgq ^ ((mrow >> 1) & 3)) * 8;   // swizzled LDS k-slot
    // (read rows are wr*64 + mi*16 + mrow; the 16-multiples don't touch the key)

    // ---- prologue: stage K-tile 0 into buf 0 ----
    GLD16(ga0, &sha[0][lofA0]);
    GLD16(ga1, &sha[0][lofA1]);
    GLD16(gb0, &shb[0][lofA0]);
    GLD16(gb1, &shb[0][lofA1]);
    __syncthreads();   // vmcnt(0)+barrier: buf0 ready

    constexpr int NK = DCH / 32;   // 12 K-tiles
#pragma unroll
    for (int t = 0; t < NK; ++t) {
        const int cur = t & 1;
        const int nxt = cur ^ 1;
        if (t < NK - 1) {
            const int kk = (t + 1) * 32;
            GLD16(ga0 + kk, &sha[nxt][lofA0]);
            GLD16(ga1 + kk, &sha[nxt][lofA1]);
            GLD16(gb0 + kk, &shb[nxt][lofA0]);
            GLD16(gb1 + kk, &shb[nxt][lofA1]);
        }
        f16x8 af[4], bfr[4];
#pragma unroll
        for (int mi = 0; mi < 4; ++mi)
            af[mi] = *(const f16x8*)(&sha[cur][(wr * 64 + mi * 16 + mrow) * 32 + kgr8]);
#pragma unroll
        for (int ni = 0; ni < 4; ++ni)
            bfr[ni] = *(const f16x8*)(&shb[cur][(wc * 64 + ni * 16 + mrow) * 32 + kgr8]);
#pragma unroll
        for (int mi = 0; mi < 4; ++mi)
#pragma unroll
            for (int ni = 0; ni < 4; ++ni)
                acc[mi][ni] = __builtin_amdgcn_mfma_f32_16x16x32_f16(
                    af[mi], bfr[ni], acc[mi][ni], 0, 0, 0);
        __syncthreads();   // drains prefetch loads (they flew under the MFMAs)
    }

    // C/D layout: col = lane&15 (p), row = (lane>>4)*4 + r (o)
    const int col = lane & 15;
    const int rq4 = (lane >> 4) * 4;
    const int qkv = ot / 3;     // 0=q 1=k 2=v
    const int grp = ot % 3;     // 128-block within the qkv group

    if (qkv < 2) {
        f16_t* Yt = (qkv == 0) ? Yq : Yk;
#pragma unroll
        for (int mi = 0; mi < 4; ++mi) {
            const int h  = grp * 4 + wr * 2 + (mi >> 1);
            const int cb = (mi & 1) * 16 + rq4;               // c base; +r consecutive
            const int ob = o0 + wr * 64 + mi * 16 + rq4;      // bias base
            const float b0 = bias[ob], b1 = bias[ob + 1];
            const float b2 = bias[ob + 2], b3 = bias[ob + 3];
#pragma unroll
            for (int ni = 0; ni < 4; ++ni) {
                const int p = p0 + wc * 64 + ni * 16 + col;
                union { uint2 u; f16_t h4[4]; } w;
                w.h4[0] = (f16_t)(acc[mi][ni][0] + b0);
                w.h4[1] = (f16_t)(acc[mi][ni][1] + b1);
                w.h4[2] = (f16_t)(acc[mi][ni][2] + b2);
                w.h4[3] = (f16_t)(acc[mi][ni][3] + b3);
                *(uint2*)(Yt + ((size_t)h * NPOS + p) * CH + cb) = w.u;
            }
        }
    } else {
#pragma unroll
        for (int mi = 0; mi < 4; ++mi) {
#pragma unroll
            for (int r = 0; r < 4; ++r) {
                const int cg = grp * 128 + wr * 64 + mi * 16 + rq4 + r;  // 0..383
                const float br = bias[768 + cg];
#pragma unroll
                for (int ni = 0; ni < 4; ++ni) {
                    const int p = p0 + wc * 64 + ni * 16 + col;
                    Yv[(size_t)cg * NPOS + p] = (f16_t)(acc[mi][ni][r] + br);
                }
            }
        }
    }
}

// ---------------------------------------------------------------------------
// MFMA axial attention, LDS-staged K/V.
// R2: Ks gets the same T2 k-group XOR swizzle (row stride 64B had the same
//     8-way conflict on every QK^T kf read). Source pre-swizzled, read XORed.
// ---------------------------------------------------------------------------
template <int SEQ, bool XT16>
__global__ __launch_bounds__(256) void mfma_attn(
        const f16_t* __restrict__ Yq, const f16_t* __restrict__ Yk,
        const f16_t* __restrict__ Yv, const void* __restrict__ Xv_,
        float* __restrict__ R)
{
    constexpr int JT  = SEQ / 16;    // j-tiles
    constexpr int NIT = SEQ / 64;    // i-tiles per wave
    constexpr int PST = SEQ + 8;     // padded P row stride (fp16 units)
    constexpr int VST = SEQ + 8;     // padded V row stride
    __shared__ f16_t Ks[SEQ * CH];       // [pos][ch-swz] — K slice
    __shared__ f16_t Vs[CH * VST];       // [ch][pos] — padded V^T slice
    __shared__ f16_t pb[4][16 * PST];
    const int tid  = threadIdx.x;
    const int lane = tid & 63;
    const int wave = tid >> 6;
    const int col = lane & 15, quad = lane >> 4;
    const int h = blockIdx.x % NH;
    const size_t pbase = (size_t)(blockIdx.x / NH) * SEQ;

    const f16_t* qg = Yq + ((size_t)h * NPOS + pbase) * CH;
    const f16_t* kg = Yk + ((size_t)h * NPOS + pbase) * CH;
    const f16_t* vg = Yv + (size_t)h * CH * NPOS + pbase;
    f16_t* mypb = pb[wave];

    // ---- stage K (async, linear dest; source k-group pre-swizzled) ----
    // lane covers (pos_local = off/32 + lane/4, kg_slot = lane&3);
    // key(pos) = (pos>>1)&3 = (lane>>3)&3 here (off/32 is a multiple of 16).
    {
        const int ksw = (lane & 3) ^ ((lane >> 3) & 3);
        const int lrow32 = (lane >> 2) * 32;
#pragma unroll
        for (int i = 0; i < SEQ / 64; ++i) {
            const int off = (wave * (SEQ / 64) + i) * 512;  // f16 units
            GLD16(kg + off + lrow32 + ksw * 8, Ks + off);
        }
    }
    // ---- stage V^T (coalesced float4, padded rows) ----
    {
        constexpr int CPR = SEQ / 8;        // 16B chunks per row
        const int vch = tid % CPR;
        const int vr0 = tid / CPR;          // rows per pass = 256/CPR
#pragma unroll
        for (int r = vr0; r < CH; r += 256 / CPR)
            *(float4*)(Vs + r * VST + vch * 8) =
                *(const float4*)(vg + (size_t)r * NPOS + vch * 8);
    }
    __syncthreads();   // drains vmcnt (K) + lgkm (V) -> LDS visible to all waves

    const int kq8 = (quad ^ ((col >> 1) & 3)) * 8;   // swizzled Ks k-slot

    for (int it = 0; it < NIT; ++it) {
        const int i0 = (wave * NIT + it) * 16;
        const f16x8 qf = *(const f16x8*)(qg + (size_t)(i0 + col) * CH + quad * 8);
        f32x4 st[JT];
#pragma unroll
        for (int mt = 0; mt < JT; ++mt) {
            f16x8 kf = *(const f16x8*)(Ks + (mt * 16 + col) * CH + kq8);
            st[mt] = __builtin_amdgcn_mfma_f32_16x16x32_f16(kf, qf, (f32x4){0.f, 0.f, 0.f, 0.f}, 0, 0, 0);
        }
        float sum = 0.f;
#pragma unroll
        for (int mt = 0; mt < JT; ++mt)
#pragma unroll
            for (int r = 0; r < 4; ++r) {
                st[mt][r] = __expf(st[mt][r]);
                sum += st[mt][r];
            }
        sum += __shfl_xor(sum, 16, 64);
        sum += __shfl_xor(sum, 32, 64);
        const float inv = 1.f / sum;
#pragma unroll
        for (int mt = 0; mt < JT; ++mt) {
            union { uint2 u; f16_t h4[4]; } w;
            w.h4[0] = (f16_t)(st[mt][0] * inv);
            w.h4[1] = (f16_t)(st[mt][1] * inv);
            w.h4[2] = (f16_t)(st[mt][2] * inv);
            w.h4[3] = (f16_t)(st[mt][3] * inv);
            *(uint2*)(mypb + col * PST + mt * 16 + quad * 4) = w.u;
        }
        WAVE_LDS_FENCE();   // per-wave pb: wave-local drain suffices

        // PV: 2 accumulation chains per output row-pair to break MFMA latency
        f32x4 o0a = {0.f, 0.f, 0.f, 0.f}, o0b = {0.f, 0.f, 0.f, 0.f};
        f32x4 o1a = {0.f, 0.f, 0.f, 0.f}, o1b = {0.f, 0.f, 0.f, 0.f};
#pragma unroll
        for (int ks = 0; ks < SEQ / 32; ks += 2) {
            f16x8 pf0 = *(const f16x8*)(mypb + col * PST + ks * 32 + quad * 8);
            f16x8 pf1 = *(const f16x8*)(mypb + col * PST + (ks + 1) * 32 + quad * 8);
            f16x8 va0 = *(const f16x8*)(Vs + col * VST + ks * 32 + quad * 8);
            f16x8 va1 = *(const f16x8*)(Vs + col * VST + (ks + 1) * 32 + quad * 8);
            f16x8 vb0 = *(const f16x8*)(Vs + (16 + col) * VST + ks * 32 + quad * 8);
            f16x8 vb1 = *(const f16x8*)(Vs + (16 + col) * VST + (ks + 1) * 32 + quad * 8);
            o0a = __builtin_amdgcn_mfma_f32_16x16x32_f16(va0, pf0, o0a, 0, 0, 0);
            o0b = __builtin_amdgcn_mfma_f32_16x16x32_f16(va1, pf1, o0b, 0, 0, 0);
            o1a = __builtin_amdgcn_mfma_f32_16x16x32_f16(vb0, pf0, o1a, 0, 0, 0);
            o1b = __builtin_amdgcn_mfma_f32_16x16x32_f16(vb1, pf1, o1b, 0, 0, 0);
        }
        const f32x4 ot0 = o0a + o0b;
        const f32x4 ot1 = o1a + o1b;

        const size_t pos = pbase + i0 + col;
        if constexpr (XT16) {
            const f16_t* Xh = (const f16_t*)Xv_;
            const f16x4 xa = *(const f16x4*)(Xh + pos * DCH + h * CH + quad * 4);
            const f16x4 xb = *(const f16x4*)(Xh + pos * DCH + h * CH + 16 + quad * 4);
#pragma unroll
            for (int r = 0; r < 4; ++r) {
                R[(size_t)(h * CH + quad * 4 + r) * NPOS + pos]      = (float)xa[r] + ot0[r];
                R[(size_t)(h * CH + 16 + quad * 4 + r) * NPOS + pos] = (float)xb[r] + ot1[r];
            }
        } else {
            const float* Xf = (const float*)Xv_;
#pragma unroll
            for (int r = 0; r < 4; ++r) {
                const size_t c0r = (size_t)(h * CH + quad * 4 + r) * NPOS + pos;
                const size_t c1r = (size_t)(h * CH + 16 + quad * 4 + r) * NPOS + pos;
                R[c0r] = Xf[c0r] + ot0[r];
                R[c1r] = Xf[c1r] + ot1[r];
            }
        }
    }
}

// ---------------------------------------------------------------------------
// LN stats: mu[p], rs[p] over the 384 channels of A[d][p].
// ---------------------------------------------------------------------------
__global__ __launch_bounds__(256) void ln_stats(const float* __restrict__ A,
                                                float* __restrict__ mu,
                                                float* __restrict__ rs) {
    __shared__ float ssum[4][64], ssq[4][64];
    const int i = threadIdx.x & 63;
    const int g = threadIdx.x >> 6;
    const int p = blockIdx.x * 64 + i;
    float sum = 0.f, sq = 0.f;
    const float* ap = A + (size_t)(g * 96) * NPOS + p;
#pragma unroll 4
    for (int d = 0; d < 96; ++d) {
        float v = ap[(size_t)d * NPOS];
        sum += v;
        sq += v * v;
    }
    ssum[g][i] = sum;
    ssq[g][i] = sq;
    __syncthreads();
    if (g == 0) {
        float s = ssum[0][i] + ssum[1][i] + ssum[2][i] + ssum[3][i];
        float q = ssq[0][i] + ssq[1][i] + ssq[2][i] + ssq[3][i];
        float m = s * (1.f / DCH);
        float var = q * (1.f / DCH) - m * m;
        mu[p] = m;
        rs[p] = rsqrtf(var + 1e-5f);
    }
}

// ---------------------------------------------------------------------------
// Fused LN-apply + transpose + fp16: A fp32 [d][s*LL+l] -> Xp fp16
// [(l*SS+s)][d].
// ---------------------------------------------------------------------------
__global__ __launch_bounds__(256) void norm_xT(
        const float* __restrict__ A, const float* __restrict__ mu,
        const float* __restrict__ rs, const float* __restrict__ w,
        const float* __restrict__ b, f16_t* __restrict__ Xp) {
    __shared__ float tile[64][65];
    const int l0 = (blockIdx.x & 3) * 64;          // LL/64 = 4
    const int s  = (blockIdx.x >> 2) & (SS - 1);   // 128
    const int k0 = (blockIdx.x >> 9) * 64;         // DCH/64 = 6
    const int tx = threadIdx.x & 63, ty = threadIdx.x >> 6;  // ty 0..3
    const int pos0 = s * LL + l0;
#pragma unroll
    for (int i = 0; i < 16; ++i) {
        const int d = k0 + ty * 16 + i;
        float v = A[(size_t)d * NPOS + pos0 + tx];
        tile[ty * 16 + i][tx] = (v - mu[pos0 + tx]) * rs[pos0 + tx] * w[d] + b[d];
    }
    __syncthreads();
    const int pr = threadIdx.x >> 2;   // l-offset 0..63
    const int cg = threadIdx.x & 3;    // 16-d group
    union { uint4 v[2]; unsigned int u[8]; } res;
#pragma unroll
    for (int j = 0; j < 8; ++j) {
        unsigned short lo = __builtin_bit_cast(unsigned short, (f16_t)tile[cg * 16 + 2 * j][pr]);
        unsigned short hi = __builtin_bit_cast(unsigned short, (f16_t)tile[cg * 16 + 2 * j + 1][pr]);
        res.u[j] = (unsigned)lo | ((unsigned)hi << 16);
    }
    uint4* dst = (uint4*)&Xp[(size_t)((l0 + pr) * SS + s) * DCH + k0 + cg * 16];
    dst[0] = res.v[0];
    dst[1] = res.v[1];
}

// ---------------------------------------------------------------------------
// Final: normalize + per-channel transpose back to original domain.
// ---------------------------------------------------------------------------
__global__ __launch_bounds__(256) void norm_transpose(
        const float* __restrict__ in, const float* __restrict__ mu,
        const float* __restrict__ rs, const float* __restrict__ w,
        const float* __restrict__ b, float* __restrict__ out, int Rr, int Cc) {
    __shared__ float tile[32][33];
    const int ntc = Cc >> 5, ntr = Rr >> 5;
    int tc = blockIdx.x % ntc;
    int tr = (blockIdx.x / ntc) % ntr;
    int d = blockIdx.x / (ntc * ntr);
    int tx = threadIdx.x & 31, ty = threadIdx.x >> 5;  // ty 0..7
    const float* ip = in + (size_t)d * Rr * Cc;
    float* op = out + (size_t)d * Rr * Cc;
    const float wd = w[d], bd = b[d];
#pragma unroll
    for (int i = 0; i < 32; i += 8) {
        const int r = tr * 32 + ty + i;
        const int c = tc * 32 + tx;
        const int pos = r * Cc + c;
        float v = ip[(size_t)r * Cc + c];
        tile[ty + i][tx] = (v - mu[pos]) * rs[pos] * wd + bd;
    }
    __syncthreads();
#pragma unroll
    for (int i = 0; i < 32; i += 8)
        op[(size_t)(tc * 32 + ty + i) * Rr + tr * 32 + tx] = tile[tx][ty + i];
}

extern "C" void kernel_launch(void* const* d_in, const int* in_sizes, int n_in,
                              void* d_out, int out_size, void* d_ws, size_t ws_size,
                              hipStream_t stream) {
    const float* x     = (const float*)d_in[0];
    const float* row_w = (const float*)d_in[1];
    const float* row_b = (const float*)d_in[2];
    const float* col_w = (const float*)d_in[3];
    const float* col_b = (const float*)d_in[4];
    const float* ln1_w = (const float*)d_in[5];
    const float* ln1_b = (const float*)d_in[6];
    const float* ln2_w = (const float*)d_in[7];
    const float* ln2_b = (const float*)d_in[8];
    float* out = (float*)d_out;

    char* ws = (char*)d_ws;
    const size_t ysz = (size_t)NH * NPOS * CH * 2;   // 25.2 MB (== DCH*NPOS*2)
    const size_t abytes = (size_t)DCH * NPOS * 4;    // 50.3 MB
    f16_t* Yq = (f16_t*)ws;
    f16_t* Yk = (f16_t*)(ws + ysz);
    f16_t* Yv = (f16_t*)(ws + 2 * ysz);
    float* A  = (float*)(ws + 3 * ysz);
    f16_t* Xp = (f16_t*)(ws + 3 * ysz + abytes);
    f16_t* Wh = (f16_t*)(ws + 3 * ysz + abytes + ysz);
    float* MU = (float*)(ws + 3 * ysz + abytes + ysz + (1 << 21));
    float* RS = MU + NPOS;

    dim3 ggrid(THREE_D / 128, NPOS / 128);   // x = o-tile (9), y = p-tile (256)
    const int wn4 = THREE_D * DCH / 4;
    dim3 cgrid(NPOS / 64, DCH / 64);

    // ---- stage 1: row attention (attend over L within each row s) ----
    conv_w<<<(wn4 + 255) / 256, 256, 0, stream>>>(row_w, Wh, wn4);
    conv_xT<<<cgrid, 256, 0, stream>>>(x, Xp);
    qkv_gemm_f16<<<ggrid, 256, 0, stream>>>(Wh, row_b, Xp, Yq, Yk, Yv);
    mfma_attn<LL, false><<<NH * SS, 256, 0, stream>>>(Yq, Yk, Yv, x, A);  // A = x + row_out
    ln_stats<<<NPOS / 64, 256, 0, stream>>>(A, MU, RS);
    norm_xT<<<(DCH / 64) * SS * (LL / 64), 256, 0, stream>>>(A, MU, RS, ln1_w, ln1_b, Xp);

    // ---- stage 2: column attention (attend over S within each column l) ----
    conv_w<<<(wn4 + 255) / 256, 256, 0, stream>>>(col_w, Wh, wn4);
    qkv_gemm_f16<<<ggrid, 256, 0, stream>>>(Wh, col_b, Xp, Yq, Yk, Yv);
    mfma_attn<SS, true><<<NH * LL, 256, 0, stream>>>(Yq, Yk, Yv, Xp, A);  // A = out1 + col_out
    ln_stats<<<NPOS / 64, 256, 0, stream>>>(A, MU, RS);
    norm_transpose<<<DCH * (LL / 32) * (SS / 32), 256, 0, stream>>>(
        A, MU, RS, ln2_w, ln2_b, out, LL, SS);
}

// Round 3
// 343.951 us; speedup vs baseline: 1.0229x; 1.0229x over previous
//
#include <hip/hip_runtime.h>
#include <math.h>

#define DCH 384
#define NH 12
#define CH 32
#define SS 128
#define LL 256
#define NPOS 32768        // SS*LL
#define THREE_D 1152

typedef _Float16 f16_t;
typedef _Float16 f16x4 __attribute__((ext_vector_type(4)));
typedef _Float16 f16x8 __attribute__((ext_vector_type(8)));
typedef float f32x4 __attribute__((ext_vector_type(4)));

// async global->LDS, 16B per lane.
// SOURCE: per-lane global address (must include lane term yourself!)
// DEST:   wave-uniform LDS base; HW adds lane*16.
#define GLD16(gptr, lptr) __builtin_amdgcn_global_load_lds( \
    (const __attribute__((address_space(1))) unsigned int*)(gptr), \
    (__attribute__((address_space(3))) unsigned int*)(lptr), 16, 0, 0)

// wave-local LDS drain: same-wave cross-lane ds_write -> ds_read ordering.
#define WAVE_LDS_FENCE() __asm__ volatile("s_waitcnt lgkmcnt(0)" ::: "memory")

// ---------------------------------------------------------------------------
// fp32 -> fp16 elementwise (weights, layout preserved). n4 = count/4.
// ---------------------------------------------------------------------------
__global__ __launch_bounds__(256) void conv_w(const float* __restrict__ in,
                                              f16_t* __restrict__ out, int n4) {
    int i = blockIdx.x * 256 + threadIdx.x;
    if (i < n4) {
        float4 v = ((const float4*)in)[i];
        unsigned short u0 = __builtin_bit_cast(unsigned short, (f16_t)v.x);
        unsigned short u1 = __builtin_bit_cast(unsigned short, (f16_t)v.y);
        unsigned short u2 = __builtin_bit_cast(unsigned short, (f16_t)v.z);
        unsigned short u3 = __builtin_bit_cast(unsigned short, (f16_t)v.w);
        uint2 r;
        r.x = (unsigned)u0 | ((unsigned)u1 << 16);
        r.y = (unsigned)u2 | ((unsigned)u3 << 16);
        ((uint2*)out)[i] = r;
    }
}

// ---------------------------------------------------------------------------
// fp32 [DCH][NPOS] -> fp16 [NPOS][DCH]  (transpose + convert, 64x64 tiles)
// ---------------------------------------------------------------------------
__global__ __launch_bounds__(256) void conv_xT(const float* __restrict__ in,
                                               f16_t* __restrict__ outp) {
    __shared__ float tile[64][65];
    const int p0 = blockIdx.x * 64;
    const int k0 = blockIdx.y * 64;
    const int tx = threadIdx.x & 63, ty = threadIdx.x >> 6;  // ty 0..3
#pragma unroll
    for (int i = 0; i < 16; ++i)
        tile[ty * 16 + i][tx] = in[(size_t)(k0 + ty * 16 + i) * NPOS + p0 + tx];
    __syncthreads();
    const int pr = threadIdx.x >> 2;   // 0..63 output row (p)
    const int cg = threadIdx.x & 3;    // 16-col group (k)
    union { uint4 v[2]; unsigned int u[8]; } res;
#pragma unroll
    for (int j = 0; j < 8; ++j) {
        unsigned short lo = __builtin_bit_cast(unsigned short, (f16_t)tile[cg * 16 + 2 * j][pr]);
        unsigned short hi = __builtin_bit_cast(unsigned short, (f16_t)tile[cg * 16 + 2 * j + 1][pr]);
        res.u[j] = (unsigned)lo | ((unsigned)hi << 16);
    }
    uint4* dst = (uint4*)&outp[(size_t)(p0 + pr) * DCH + k0 + cg * 16];
    dst[0] = res.v[0];
    dst[1] = res.v[1];
}

// ---------------------------------------------------------------------------
// fp16 MFMA GEMM producing attention-friendly fp16 outputs:
//   q,k -> Yq/Yk [NH][NPOS][CH]   (p-major rows of 32 ch: direct MFMA frags)
//   v   -> Yv [DCH][NPOS]         (c-major: V^T A-frag rows)
//
// R1: 2-phase dbuf prefetch + bijective XCD swizzle (FETCH 115->18MB).
// R2: T2 k-group XOR swizzle (bank conflicts 3.54M -> 0; dur unchanged ->
//     drain-bound, not LDS-bound).
// R3: T4 counted-vmcnt pipeline. Depth-2 prefetch into 3 LDS buffers;
//     per-iteration end = s_waitcnt vmcnt(4) + RAW s_barrier (never drains
//     the tile-(t+2) loads issued this step). Each load gets ~2 step-times
//     to fly -> L2 latency off the critical path.
// ---------------------------------------------------------------------------
__global__ __launch_bounds__(256) void qkv_gemm_f16(
        const f16_t* __restrict__ Wh,    // [THREE_D][DCH]
        const float* __restrict__ bias,  // [THREE_D]
        const f16_t* __restrict__ Xp,    // [NPOS][DCH]
        f16_t* __restrict__ Yq, f16_t* __restrict__ Yk, f16_t* __restrict__ Yv)
{
    __shared__ f16_t sha[3][128 * 32];  // [buf][o_local][k-swz] 3x8 KB
    __shared__ f16_t shb[3][128 * 32];  // [buf][p_local][k-swz] 3x8 KB
    const int tid  = threadIdx.x;
    const int lane = tid & 63;
    const int wave = tid >> 6;

    // Bijective XCD swizzle: nwg = 9*256 = 2304 = 8 * 288.
    const int hwid = blockIdx.y * 9 + blockIdx.x;      // x fastest in dispatch
    const int nid  = (hwid & 7) * 288 + (hwid >> 3);
    const int ot   = nid % 9;                           // 0..8
    const int pt   = nid / 9;                           // 0..255
    const int o0 = ot * 128;
    const int p0 = pt * 128;
    const int wr = wave >> 1, wc = wave & 1;   // 2x2 wave grid

    f32x4 acc[4][4] = {};

    // staging: lane covers (row = c>>2, kg_slot = c&3); source k-group is
    // pre-swizzled so that LDS slot (row, kg_slot) holds data kg_slot^key(row).
    const int c0 = wave * 128 + lane;
    const int c1 = c0 + 64;
    const int r0 = c0 >> 2, r1 = c1 >> 2;
    const int kg0 = (c0 & 3) ^ ((r0 >> 1) & 3);
    const int kg1 = (c1 & 3) ^ ((r1 >> 1) & 3);
    const f16_t* ga0 = Wh + (size_t)(o0 + r0) * DCH + kg0 * 8;
    const f16_t* ga1 = Wh + (size_t)(o0 + r1) * DCH + kg1 * 8;
    const f16_t* gb0 = Xp + (size_t)(p0 + r0) * DCH + kg0 * 8;
    const f16_t* gb1 = Xp + (size_t)(p0 + r1) * DCH + kg1 * 8;
    const int lofA0 = (wave * 128) * 8;        // f16 units, wave-uniform base
    const int lofA1 = (wave * 128 + 64) * 8;

    const int mrow = lane & 15;
    const int kgq  = lane >> 4;                       // fragment k-group 0..3
    const int kgr8 = (kgq ^ ((mrow >> 1) & 3)) * 8;   // swizzled LDS k-slot

    constexpr int NK = DCH / 32;   // 12 K-tiles

    // ---- prologue: stage tiles 0 and 1 (4 loads/wave each) ----
    GLD16(ga0, &sha[0][lofA0]);
    GLD16(ga1, &sha[0][lofA1]);
    GLD16(gb0, &shb[0][lofA0]);
    GLD16(gb1, &shb[0][lofA1]);
    GLD16(ga0 + 32, &sha[1][lofA0]);
    GLD16(ga1 + 32, &sha[1][lofA1]);
    GLD16(gb0 + 32, &shb[1][lofA0]);
    GLD16(gb1 + 32, &shb[1][lofA1]);
    __asm__ volatile("s_waitcnt vmcnt(4)" ::: "memory");   // tile 0 landed
    __builtin_amdgcn_s_barrier();
    __asm__ volatile("" ::: "memory");

#pragma unroll
    for (int t = 0; t < NK; ++t) {
        const int cur = t % 3;
        // issue tile t+2 (its buffer held tile t-1: reads done pre-barrier)
        if (t + 2 < NK) {
            const int nxt = (t + 2) % 3;
            const int kk = (t + 2) * 32;
            GLD16(ga0 + kk, &sha[nxt][lofA0]);
            GLD16(ga1 + kk, &sha[nxt][lofA1]);
            GLD16(gb0 + kk, &shb[nxt][lofA0]);
            GLD16(gb1 + kk, &shb[nxt][lofA1]);
        }
        f16x8 af[4], bfr[4];
#pragma unroll
        for (int mi = 0; mi < 4; ++mi)
            af[mi] = *(const f16x8*)(&sha[cur][(wr * 64 + mi * 16 + mrow) * 32 + kgr8]);
#pragma unroll
        for (int ni = 0; ni < 4; ++ni)
            bfr[ni] = *(const f16x8*)(&shb[cur][(wc * 64 + ni * 16 + mrow) * 32 + kgr8]);
#pragma unroll
        for (int mi = 0; mi < 4; ++mi)
#pragma unroll
            for (int ni = 0; ni < 4; ++ni)
                acc[mi][ni] = __builtin_amdgcn_mfma_f32_16x16x32_f16(
                    af[mi], bfr[ni], acc[mi][ni], 0, 0, 0);
        // counted drain: only tile t+1's loads (oldest 4) must land;
        // tile t+2's 4 stay in flight across the barrier.
        if (t < NK - 2) {
            __asm__ volatile("s_waitcnt vmcnt(4)" ::: "memory");
            __builtin_amdgcn_s_barrier();
            __asm__ volatile("" ::: "memory");
        } else if (t == NK - 2) {
            __asm__ volatile("s_waitcnt vmcnt(0)" ::: "memory");
            __builtin_amdgcn_s_barrier();
            __asm__ volatile("" ::: "memory");
        }
        // t == NK-1: no further LDS reads; fall through to epilogue
    }

    // C/D layout: col = lane&15 (p), row = (lane>>4)*4 + r (o)
    const int col = lane & 15;
    const int rq4 = (lane >> 4) * 4;
    const int qkv = ot / 3;     // 0=q 1=k 2=v
    const int grp = ot % 3;     // 128-block within the qkv group

    if (qkv < 2) {
        f16_t* Yt = (qkv == 0) ? Yq : Yk;
#pragma unroll
        for (int mi = 0; mi < 4; ++mi) {
            const int h  = grp * 4 + wr * 2 + (mi >> 1);
            const int cb = (mi & 1) * 16 + rq4;               // c base; +r consecutive
            const int ob = o0 + wr * 64 + mi * 16 + rq4;      // bias base
            const float b0 = bias[ob], b1 = bias[ob + 1];
            const float b2 = bias[ob + 2], b3 = bias[ob + 3];
#pragma unroll
            for (int ni = 0; ni < 4; ++ni) {
                const int p = p0 + wc * 64 + ni * 16 + col;
                union { uint2 u; f16_t h4[4]; } w;
                w.h4[0] = (f16_t)(acc[mi][ni][0] + b0);
                w.h4[1] = (f16_t)(acc[mi][ni][1] + b1);
                w.h4[2] = (f16_t)(acc[mi][ni][2] + b2);
                w.h4[3] = (f16_t)(acc[mi][ni][3] + b3);
                *(uint2*)(Yt + ((size_t)h * NPOS + p) * CH + cb) = w.u;
            }
        }
    } else {
#pragma unroll
        for (int mi = 0; mi < 4; ++mi) {
#pragma unroll
            for (int r = 0; r < 4; ++r) {
                const int cg = grp * 128 + wr * 64 + mi * 16 + rq4 + r;  // 0..383
                const float br = bias[768 + cg];
#pragma unroll
                for (int ni = 0; ni < 4; ++ni) {
                    const int p = p0 + wc * 64 + ni * 16 + col;
                    Yv[(size_t)cg * NPOS + p] = (f16_t)(acc[mi][ni][r] + br);
                }
            }
        }
    }
}

// ---------------------------------------------------------------------------
// MFMA axial attention, LDS-staged K/V.
// R2: Ks k-group XOR swizzle (source pre-swizzled, read XORed).
// ---------------------------------------------------------------------------
template <int SEQ, bool XT16>
__global__ __launch_bounds__(256) void mfma_attn(
        const f16_t* __restrict__ Yq, const f16_t* __restrict__ Yk,
        const f16_t* __restrict__ Yv, const void* __restrict__ Xv_,
        float* __restrict__ R)
{
    constexpr int JT  = SEQ / 16;    // j-tiles
    constexpr int NIT = SEQ / 64;    // i-tiles per wave
    constexpr int PST = SEQ + 8;     // padded P row stride (fp16 units)
    constexpr int VST = SEQ + 8;     // padded V row stride
    __shared__ f16_t Ks[SEQ * CH];       // [pos][ch-swz] — K slice
    __shared__ f16_t Vs[CH * VST];       // [ch][pos] — padded V^T slice
    __shared__ f16_t pb[4][16 * PST];
    const int tid  = threadIdx.x;
    const int lane = tid & 63;
    const int wave = tid >> 6;
    const int col = lane & 15, quad = lane >> 4;
    const int h = blockIdx.x % NH;
    const size_t pbase = (size_t)(blockIdx.x / NH) * SEQ;

    const f16_t* qg = Yq + ((size_t)h * NPOS + pbase) * CH;
    const f16_t* kg = Yk + ((size_t)h * NPOS + pbase) * CH;
    const f16_t* vg = Yv + (size_t)h * CH * NPOS + pbase;
    f16_t* mypb = pb[wave];

    // ---- stage K (async, linear dest; source k-group pre-swizzled) ----
    {
        const int ksw = (lane & 3) ^ ((lane >> 3) & 3);
        const int lrow32 = (lane >> 2) * 32;
#pragma unroll
        for (int i = 0; i < SEQ / 64; ++i) {
            const int off = (wave * (SEQ / 64) + i) * 512;  // f16 units
            GLD16(kg + off + lrow32 + ksw * 8, Ks + off);
        }
    }
    // ---- stage V^T (coalesced float4, padded rows) ----
    {
        constexpr int CPR = SEQ / 8;        // 16B chunks per row
        const int vch = tid % CPR;
        const int vr0 = tid / CPR;          // rows per pass = 256/CPR
#pragma unroll
        for (int r = vr0; r < CH; r += 256 / CPR)
            *(float4*)(Vs + r * VST + vch * 8) =
                *(const float4*)(vg + (size_t)r * NPOS + vch * 8);
    }
    __syncthreads();   // drains vmcnt (K) + lgkm (V) -> LDS visible to all waves

    const int kq8 = (quad ^ ((col >> 1) & 3)) * 8;   // swizzled Ks k-slot

    for (int it = 0; it < NIT; ++it) {
        const int i0 = (wave * NIT + it) * 16;
        const f16x8 qf = *(const f16x8*)(qg + (size_t)(i0 + col) * CH + quad * 8);
        f32x4 st[JT];
#pragma unroll
        for (int mt = 0; mt < JT; ++mt) {
            f16x8 kf = *(const f16x8*)(Ks + (mt * 16 + col) * CH + kq8);
            st[mt] = __builtin_amdgcn_mfma_f32_16x16x32_f16(kf, qf, (f32x4){0.f, 0.f, 0.f, 0.f}, 0, 0, 0);
        }
        float sum = 0.f;
#pragma unroll
        for (int mt = 0; mt < JT; ++mt)
#pragma unroll
            for (int r = 0; r < 4; ++r) {
                st[mt][r] = __expf(st[mt][r]);
                sum += st[mt][r];
            }
        sum += __shfl_xor(sum, 16, 64);
        sum += __shfl_xor(sum, 32, 64);
        const float inv = 1.f / sum;
#pragma unroll
        for (int mt = 0; mt < JT; ++mt) {
            union { uint2 u; f16_t h4[4]; } w;
            w.h4[0] = (f16_t)(st[mt][0] * inv);
            w.h4[1] = (f16_t)(st[mt][1] * inv);
            w.h4[2] = (f16_t)(st[mt][2] * inv);
            w.h4[3] = (f16_t)(st[mt][3] * inv);
            *(uint2*)(mypb + col * PST + mt * 16 + quad * 4) = w.u;
        }
        WAVE_LDS_FENCE();   // per-wave pb: wave-local drain suffices

        // PV: 2 accumulation chains per output row-pair to break MFMA latency
        f32x4 o0a = {0.f, 0.f, 0.f, 0.f}, o0b = {0.f, 0.f, 0.f, 0.f};
        f32x4 o1a = {0.f, 0.f, 0.f, 0.f}, o1b = {0.f, 0.f, 0.f, 0.f};
#pragma unroll
        for (int ks = 0; ks < SEQ / 32; ks += 2) {
            f16x8 pf0 = *(const f16x8*)(mypb + col * PST + ks * 32 + quad * 8);
            f16x8 pf1 = *(const f16x8*)(mypb + col * PST + (ks + 1) * 32 + quad * 8);
            f16x8 va0 = *(const f16x8*)(Vs + col * VST + ks * 32 + quad * 8);
            f16x8 va1 = *(const f16x8*)(Vs + col * VST + (ks + 1) * 32 + quad * 8);
            f16x8 vb0 = *(const f16x8*)(Vs + (16 + col) * VST + ks * 32 + quad * 8);
            f16x8 vb1 = *(const f16x8*)(Vs + (16 + col) * VST + (ks + 1) * 32 + quad * 8);
            o0a = __builtin_amdgcn_mfma_f32_16x16x32_f16(va0, pf0, o0a, 0, 0, 0);
            o0b = __builtin_amdgcn_mfma_f32_16x16x32_f16(va1, pf1, o0b, 0, 0, 0);
            o1a = __builtin_amdgcn_mfma_f32_16x16x32_f16(vb0, pf0, o1a, 0, 0, 0);
            o1b = __builtin_amdgcn_mfma_f32_16x16x32_f16(vb1, pf1, o1b, 0, 0, 0);
        }
        const f32x4 ot0 = o0a + o0b;
        const f32x4 ot1 = o1a + o1b;

        const size_t pos = pbase + i0 + col;
        if constexpr (XT16) {
            const f16_t* Xh = (const f16_t*)Xv_;
            const f16x4 xa = *(const f16x4*)(Xh + pos * DCH + h * CH + quad * 4);
            const f16x4 xb = *(const f16x4*)(Xh + pos * DCH + h * CH + 16 + quad * 4);
#pragma unroll
            for (int r = 0; r < 4; ++r) {
                R[(size_t)(h * CH + quad * 4 + r) * NPOS + pos]      = (float)xa[r] + ot0[r];
                R[(size_t)(h * CH + 16 + quad * 4 + r) * NPOS + pos] = (float)xb[r] + ot1[r];
            }
        } else {
            const float* Xf = (const float*)Xv_;
#pragma unroll
            for (int r = 0; r < 4; ++r) {
                const size_t c0r = (size_t)(h * CH + quad * 4 + r) * NPOS + pos;
                const size_t c1r = (size_t)(h * CH + 16 + quad * 4 + r) * NPOS + pos;
                R[c0r] = Xf[c0r] + ot0[r];
                R[c1r] = Xf[c1r] + ot1[r];
            }
        }
    }
}

// ---------------------------------------------------------------------------
// LN stats: mu[p], rs[p] over the 384 channels of A[d][p].
// ---------------------------------------------------------------------------
__global__ __launch_bounds__(256) void ln_stats(const float* __restrict__ A,
                                                float* __restrict__ mu,
                                                float* __restrict__ rs) {
    __shared__ float ssum[4][64], ssq[4][64];
    const int i = threadIdx.x & 63;
    const int g = threadIdx.x >> 6;
    const int p = blockIdx.x * 64 + i;
    float sum = 0.f, sq = 0.f;
    const float* ap = A + (size_t)(g * 96) * NPOS + p;
#pragma unroll 4
    for (int d = 0; d < 96; ++d) {
        float v = ap[(size_t)d * NPOS];
        sum += v;
        sq += v * v;
    }
    ssum[g][i] = sum;
    ssq[g][i] = sq;
    __syncthreads();
    if (g == 0) {
        float s = ssum[0][i] + ssum[1][i] + ssum[2][i] + ssum[3][i];
        float q = ssq[0][i] + ssq[1][i] + ssq[2][i] + ssq[3][i];
        float m = s * (1.f / DCH);
        float var = q * (1.f / DCH) - m * m;
        mu[p] = m;
        rs[p] = rsqrtf(var + 1e-5f);
    }
}

// ---------------------------------------------------------------------------
// Fused LN-apply + transpose + fp16: A fp32 [d][s*LL+l] -> Xp fp16
// [(l*SS+s)][d].
// ---------------------------------------------------------------------------
__global__ __launch_bounds__(256) void norm_xT(
        const float* __restrict__ A, const float* __restrict__ mu,
        const float* __restrict__ rs, const float* __restrict__ w,
        const float* __restrict__ b, f16_t* __restrict__ Xp) {
    __shared__ float tile[64][65];
    const int l0 = (blockIdx.x & 3) * 64;          // LL/64 = 4
    const int s  = (blockIdx.x >> 2) & (SS - 1);   // 128
    const int k0 = (blockIdx.x >> 9) * 64;         // DCH/64 = 6
    const int tx = threadIdx.x & 63, ty = threadIdx.x >> 6;  // ty 0..3
    const int pos0 = s * LL + l0;
#pragma unroll
    for (int i = 0; i < 16; ++i) {
        const int d = k0 + ty * 16 + i;
        float v = A[(size_t)d * NPOS + pos0 + tx];
        tile[ty * 16 + i][tx] = (v - mu[pos0 + tx]) * rs[pos0 + tx] * w[d] + b[d];
    }
    __syncthreads();
    const int pr = threadIdx.x >> 2;   // l-offset 0..63
    const int cg = threadIdx.x & 3;    // 16-d group
    union { uint4 v[2]; unsigned int u[8]; } res;
#pragma unroll
    for (int j = 0; j < 8; ++j) {
        unsigned short lo = __builtin_bit_cast(unsigned short, (f16_t)tile[cg * 16 + 2 * j][pr]);
        unsigned short hi = __builtin_bit_cast(unsigned short, (f16_t)tile[cg * 16 + 2 * j + 1][pr]);
        res.u[j] = (unsigned)lo | ((unsigned)hi << 16);
    }
    uint4* dst = (uint4*)&Xp[(size_t)((l0 + pr) * SS + s) * DCH + k0 + cg * 16];
    dst[0] = res.v[0];
    dst[1] = res.v[1];
}

// ---------------------------------------------------------------------------
// Final: normalize + per-channel transpose back to original domain.
// ---------------------------------------------------------------------------
__global__ __launch_bounds__(256) void norm_transpose(
        const float* __restrict__ in, const float* __restrict__ mu,
        const float* __restrict__ rs, const float* __restrict__ w,
        const float* __restrict__ b, float* __restrict__ out, int Rr, int Cc) {
    __shared__ float tile[32][33];
    const int ntc = Cc >> 5, ntr = Rr >> 5;
    int tc = blockIdx.x % ntc;
    int tr = (blockIdx.x / ntc) % ntr;
    int d = blockIdx.x / (ntc * ntr);
    int tx = threadIdx.x & 31, ty = threadIdx.x >> 5;  // ty 0..7
    const float* ip = in + (size_t)d * Rr * Cc;
    float* op = out + (size_t)d * Rr * Cc;
    const float wd = w[d], bd = b[d];
#pragma unroll
    for (int i = 0; i < 32; i += 8) {
        const int r = tr * 32 + ty + i;
        const int c = tc * 32 + tx;
        const int pos = r * Cc + c;
        float v = ip[(size_t)r * Cc + c];
        tile[ty + i][tx] = (v - mu[pos]) * rs[pos] * wd + bd;
    }
    __syncthreads();
#pragma unroll
    for (int i = 0; i < 32; i += 8)
        op[(size_t)(tc * 32 + ty + i) * Rr + tr * 32 + tx] = tile[tx][ty + i];
}

extern "C" void kernel_launch(void* const* d_in, const int* in_sizes, int n_in,
                              void* d_out, int out_size, void* d_ws, size_t ws_size,
                              hipStream_t stream) {
    const float* x     = (const float*)d_in[0];
    const float* row_w = (const float*)d_in[1];
    const float* row_b = (const float*)d_in[2];
    const float* col_w = (const float*)d_in[3];
    const float* col_b = (const float*)d_in[4];
    const float* ln1_w = (const float*)d_in[5];
    const float* ln1_b = (const float*)d_in[6];
    const float* ln2_w = (const float*)d_in[7];
    const float* ln2_b = (const float*)d_in[8];
    float* out = (float*)d_out;

    char* ws = (char*)d_ws;
    const size_t ysz = (size_t)NH * NPOS * CH * 2;   // 25.2 MB (== DCH*NPOS*2)
    const size_t abytes = (size_t)DCH * NPOS * 4;    // 50.3 MB
    f16_t* Yq = (f16_t*)ws;
    f16_t* Yk = (f16_t*)(ws + ysz);
    f16_t* Yv = (f16_t*)(ws + 2 * ysz);
    float* A  = (float*)(ws + 3 * ysz);
    f16_t* Xp = (f16_t*)(ws + 3 * ysz + abytes);
    f16_t* Wh = (f16_t*)(ws + 3 * ysz + abytes + ysz);
    float* MU = (float*)(ws + 3 * ysz + abytes + ysz + (1 << 21));
    float* RS = MU + NPOS;

    dim3 ggrid(THREE_D / 128, NPOS / 128);   // x = o-tile (9), y = p-tile (256)
    const int wn4 = THREE_D * DCH / 4;
    dim3 cgrid(NPOS / 64, DCH / 64);

    // ---- stage 1: row attention (attend over L within each row s) ----
    conv_w<<<(wn4 + 255) / 256, 256, 0, stream>>>(row_w, Wh, wn4);
    conv_xT<<<cgrid, 256, 0, stream>>>(x, Xp);
    qkv_gemm_f16<<<ggrid, 256, 0, stream>>>(Wh, row_b, Xp, Yq, Yk, Yv);
    mfma_attn<LL, false><<<NH * SS, 256, 0, stream>>>(Yq, Yk, Yv, x, A);  // A = x + row_out
    ln_stats<<<NPOS / 64, 256, 0, stream>>>(A, MU, RS);
    norm_xT<<<(DCH / 64) * SS * (LL / 64), 256, 0, stream>>>(A, MU, RS, ln1_w, ln1_b, Xp);

    // ---- stage 2: column attention (attend over S within each column l) ----
    conv_w<<<(wn4 + 255) / 256, 256, 0, stream>>>(col_w, Wh, wn4);
    qkv_gemm_f16<<<ggrid, 256, 0, stream>>>(Wh, col_b, Xp, Yq, Yk, Yv);
    mfma_attn<SS, true><<<NH * LL, 256, 0, stream>>>(Yq, Yk, Yv, Xp, A);  // A = out1 + col_out
    ln_stats<<<NPOS / 64, 256, 0, stream>>>(A, MU, RS);
    norm_transpose<<<DCH * (LL / 32) * (SS / 32), 256, 0, stream>>>(
        A, MU, RS, ln2_w, ln2_b, out, LL, SS);
}

// Round 4
// 342.778 us; speedup vs baseline: 1.0264x; 1.0034x over previous
//
#include <hip/hip_runtime.h>
#include <math.h>

#define DCH 384
#define NH 12
#define CH 32
#define SS 128
#define LL 256
#define NPOS 32768        // SS*LL
#define THREE_D 1152

typedef _Float16 f16_t;
typedef _Float16 f16x4 __attribute__((ext_vector_type(4)));
typedef _Float16 f16x8 __attribute__((ext_vector_type(8)));
typedef float f32x4 __attribute__((ext_vector_type(4)));

// async global->LDS, 16B per lane.
// SOURCE: per-lane global address (must include lane term yourself!)
// DEST:   wave-uniform LDS base; HW adds lane*16.
#define GLD16(gptr, lptr) __builtin_amdgcn_global_load_lds( \
    (const __attribute__((address_space(1))) unsigned int*)(gptr), \
    (__attribute__((address_space(3))) unsigned int*)(lptr), 16, 0, 0)

// wave-local LDS drain: same-wave cross-lane ds_write -> ds_read ordering.
#define WAVE_LDS_FENCE() __asm__ volatile("s_waitcnt lgkmcnt(0)" ::: "memory")

// ---------------------------------------------------------------------------
// fp32 -> fp16 elementwise (weights, layout preserved). n4 = count/4.
// ---------------------------------------------------------------------------
__global__ __launch_bounds__(256) void conv_w(const float* __restrict__ in,
                                              f16_t* __restrict__ out, int n4) {
    int i = blockIdx.x * 256 + threadIdx.x;
    if (i < n4) {
        float4 v = ((const float4*)in)[i];
        unsigned short u0 = __builtin_bit_cast(unsigned short, (f16_t)v.x);
        unsigned short u1 = __builtin_bit_cast(unsigned short, (f16_t)v.y);
        unsigned short u2 = __builtin_bit_cast(unsigned short, (f16_t)v.z);
        unsigned short u3 = __builtin_bit_cast(unsigned short, (f16_t)v.w);
        uint2 r;
        r.x = (unsigned)u0 | ((unsigned)u1 << 16);
        r.y = (unsigned)u2 | ((unsigned)u3 << 16);
        ((uint2*)out)[i] = r;
    }
}

// ---------------------------------------------------------------------------
// fp32 [DCH][NPOS] -> fp16 [NPOS][DCH]  (transpose + convert, 64x64 tiles)
// ---------------------------------------------------------------------------
__global__ __launch_bounds__(256) void conv_xT(const float* __restrict__ in,
                                               f16_t* __restrict__ outp) {
    __shared__ float tile[64][65];
    const int p0 = blockIdx.x * 64;
    const int k0 = blockIdx.y * 64;
    const int tx = threadIdx.x & 63, ty = threadIdx.x >> 6;  // ty 0..3
#pragma unroll
    for (int i = 0; i < 16; ++i)
        tile[ty * 16 + i][tx] = in[(size_t)(k0 + ty * 16 + i) * NPOS + p0 + tx];
    __syncthreads();
    const int pr = threadIdx.x >> 2;   // 0..63 output row (p)
    const int cg = threadIdx.x & 3;    // 16-col group (k)
    union { uint4 v[2]; unsigned int u[8]; } res;
#pragma unroll
    for (int j = 0; j < 8; ++j) {
        unsigned short lo = __builtin_bit_cast(unsigned short, (f16_t)tile[cg * 16 + 2 * j][pr]);
        unsigned short hi = __builtin_bit_cast(unsigned short, (f16_t)tile[cg * 16 + 2 * j + 1][pr]);
        res.u[j] = (unsigned)lo | ((unsigned)hi << 16);
    }
    uint4* dst = (uint4*)&outp[(size_t)(p0 + pr) * DCH + k0 + cg * 16];
    dst[0] = res.v[0];
    dst[1] = res.v[1];
}

// ---------------------------------------------------------------------------
// fp16 MFMA GEMM producing attention-friendly fp16 outputs:
//   q,k -> Yq/Yk [NH][NPOS][CH]   (p-major rows of 32 ch: direct MFMA frags)
//   v   -> Yv [DCH][NPOS]         (c-major: V^T A-frag rows)
//
// R4: barrier-free K-loop. K=384 is small enough that the WHOLE 128x384
//     A-tile (W panel, 96 KB fp16) stages into LDS once (single barrier).
//     B (X) fragments stream global->register (64B-line coalesced by
//     construction: 16 lanes = 16 full lines), depth-2 rotating prefetch.
//     No per-K-step barrier, no LDS WAR hazards: waves fully decoupled,
//     compiler emits fine-grained per-register vmcnt/lgkmcnt.
//     8 waves, tile 128(o) x 256(p); wave w owns o 0..127, p w*32..w*32+31.
//     A-LDS conflict-free via slot-XOR swizzle: slot' = slot ^ (row&7)
//     (source pre-swizzled for linear GLD16 dest; read applies same XOR).
// ---------------------------------------------------------------------------
__global__ __launch_bounds__(512) void qkv_gemm_f16(
        const f16_t* __restrict__ Wh,    // [THREE_D][DCH]
        const float* __restrict__ bias,  // [THREE_D]
        const f16_t* __restrict__ Xp,    // [NPOS][DCH]
        f16_t* __restrict__ Yq, f16_t* __restrict__ Yk, f16_t* __restrict__ Yv)
{
    __shared__ f16_t sha[128 * 384];   // 96 KB; [row][slot^key] 16B slots
    const int tid  = threadIdx.x;
    const int lane = tid & 63;
    const int wave = tid >> 6;         // 0..7

    // Bijective XCD swizzle: nwg = 9*128 = 1152 = 8 * 144.
    const int hwid = blockIdx.y * 9 + blockIdx.x;      // x fastest in dispatch
    const int nid  = (hwid & 7) * 144 + (hwid >> 3);
    const int ot   = nid % 9;                           // 0..8
    const int pt   = nid / 9;                           // 0..127
    const int o0 = ot * 128;
    const int p0 = pt * 256;

    const int mrow = lane & 15;
    const int kgq  = lane >> 4;        // k-quad 0..3

    // ---- stage whole A panel (128 rows x 48 slots of 16B), once ----
    // slot linear index i = row*48 + s; LDS slot s of row holds data
    // k-group g = s ^ (row&7)  (XOR involution; source pre-swizzled).
#pragma unroll
    for (int j = 0; j < 12; ++j) {
        const int ibase = (wave * 12 + j) * 64;   // wave-uniform slot base
        const int i = ibase + lane;
        const int row = i / 48;
        const int s = i - row * 48;
        const int g = s ^ (row & 7);
        GLD16(Wh + (size_t)(o0 + row) * DCH + g * 8, sha + (size_t)ibase * 8);
    }

    // ---- B reg-stream bases (per-lane). Wave w covers p rows w*32..+31:
    //      ni=0 -> rows w*32+mrow, ni=1 -> rows w*32+16+mrow. ----
    const f16_t* bp0 = Xp + (size_t)(p0 + wave * 32 + mrow) * DCH + kgq * 8;
    const f16_t* bp1 = bp0 + (size_t)16 * DCH;

    f32x4 acc[8][2] = {};
    f16x8 breg[3][2];

    // prefetch B tiles 0,1 while A staging drains
    breg[0][0] = *(const f16x8*)(bp0);
    breg[0][1] = *(const f16x8*)(bp1);
    breg[1][0] = *(const f16x8*)(bp0 + 32);
    breg[1][1] = *(const f16x8*)(bp1 + 32);

    __syncthreads();   // the ONLY barrier: A panel visible to all waves

    const int key = mrow & 7;          // read rows are mi*16+mrow -> key const
    constexpr int NK = DCH / 32;       // 12
#pragma unroll
    for (int t = 0; t < NK; ++t) {
        if (t + 2 < NK) {
            breg[(t + 2) % 3][0] = *(const f16x8*)(bp0 + (t + 2) * 32);
            breg[(t + 2) % 3][1] = *(const f16x8*)(bp1 + (t + 2) * 32);
        }
        const int soff = ((t * 4 + kgq) ^ key) * 8;   // swizzled slot offset
#pragma unroll
        for (int mi = 0; mi < 8; ++mi) {
            const f16x8 a = *(const f16x8*)(sha + (size_t)(mi * 16 + mrow) * DCH + soff);
            acc[mi][0] = __builtin_amdgcn_mfma_f32_16x16x32_f16(
                a, breg[t % 3][0], acc[mi][0], 0, 0, 0);
            acc[mi][1] = __builtin_amdgcn_mfma_f32_16x16x32_f16(
                a, breg[t % 3][1], acc[mi][1], 0, 0, 0);
        }
    }

    // C/D layout: col = lane&15 (p), row = (lane>>4)*4 + r (o)
    const int col = lane & 15;
    const int rq4 = (lane >> 4) * 4;
    const int qkv = ot / 3;     // 0=q 1=k 2=v
    const int grp = ot % 3;     // 128-block within the qkv group

    if (qkv < 2) {
        f16_t* Yt = (qkv == 0) ? Yq : Yk;
#pragma unroll
        for (int mi = 0; mi < 8; ++mi) {
            const int h  = grp * 4 + (mi >> 1);
            const int cb = (mi & 1) * 16 + rq4;               // c base; +r consecutive
            const int ob = o0 + mi * 16 + rq4;                // bias base
            const float b0 = bias[ob], b1 = bias[ob + 1];
            const float b2 = bias[ob + 2], b3 = bias[ob + 3];
#pragma unroll
            for (int ni = 0; ni < 2; ++ni) {
                const int p = p0 + wave * 32 + ni * 16 + col;
                union { uint2 u; f16_t h4[4]; } w;
                w.h4[0] = (f16_t)(acc[mi][ni][0] + b0);
                w.h4[1] = (f16_t)(acc[mi][ni][1] + b1);
                w.h4[2] = (f16_t)(acc[mi][ni][2] + b2);
                w.h4[3] = (f16_t)(acc[mi][ni][3] + b3);
                *(uint2*)(Yt + ((size_t)h * NPOS + p) * CH + cb) = w.u;
            }
        }
    } else {
#pragma unroll
        for (int mi = 0; mi < 8; ++mi) {
#pragma unroll
            for (int r = 0; r < 4; ++r) {
                const int cg = grp * 128 + mi * 16 + rq4 + r;  // 0..383
                const float br = bias[768 + cg];
#pragma unroll
                for (int ni = 0; ni < 2; ++ni) {
                    const int p = p0 + wave * 32 + ni * 16 + col;
                    Yv[(size_t)cg * NPOS + p] = (f16_t)(acc[mi][ni][r] + br);
                }
            }
        }
    }
}

// ---------------------------------------------------------------------------
// MFMA axial attention, LDS-staged K/V.
// R2: Ks k-group XOR swizzle (source pre-swizzled, read XORed).
// ---------------------------------------------------------------------------
template <int SEQ, bool XT16>
__global__ __launch_bounds__(256) void mfma_attn(
        const f16_t* __restrict__ Yq, const f16_t* __restrict__ Yk,
        const f16_t* __restrict__ Yv, const void* __restrict__ Xv_,
        float* __restrict__ R)
{
    constexpr int JT  = SEQ / 16;    // j-tiles
    constexpr int NIT = SEQ / 64;    // i-tiles per wave
    constexpr int PST = SEQ + 8;     // padded P row stride (fp16 units)
    constexpr int VST = SEQ + 8;     // padded V row stride
    __shared__ f16_t Ks[SEQ * CH];       // [pos][ch-swz] — K slice
    __shared__ f16_t Vs[CH * VST];       // [ch][pos] — padded V^T slice
    __shared__ f16_t pb[4][16 * PST];
    const int tid  = threadIdx.x;
    const int lane = tid & 63;
    const int wave = tid >> 6;
    const int col = lane & 15, quad = lane >> 4;
    const int h = blockIdx.x % NH;
    const size_t pbase = (size_t)(blockIdx.x / NH) * SEQ;

    const f16_t* qg = Yq + ((size_t)h * NPOS + pbase) * CH;
    const f16_t* kg = Yk + ((size_t)h * NPOS + pbase) * CH;
    const f16_t* vg = Yv + (size_t)h * CH * NPOS + pbase;
    f16_t* mypb = pb[wave];

    // ---- stage K (async, linear dest; source k-group pre-swizzled) ----
    {
        const int ksw = (lane & 3) ^ ((lane >> 3) & 3);
        const int lrow32 = (lane >> 2) * 32;
#pragma unroll
        for (int i = 0; i < SEQ / 64; ++i) {
            const int off = (wave * (SEQ / 64) + i) * 512;  // f16 units
            GLD16(kg + off + lrow32 + ksw * 8, Ks + off);
        }
    }
    // ---- stage V^T (coalesced float4, padded rows) ----
    {
        constexpr int CPR = SEQ / 8;        // 16B chunks per row
        const int vch = tid % CPR;
        const int vr0 = tid / CPR;          // rows per pass = 256/CPR
#pragma unroll
        for (int r = vr0; r < CH; r += 256 / CPR)
            *(float4*)(Vs + r * VST + vch * 8) =
                *(const float4*)(vg + (size_t)r * NPOS + vch * 8);
    }
    __syncthreads();   // drains vmcnt (K) + lgkm (V) -> LDS visible to all waves

    const int kq8 = (quad ^ ((col >> 1) & 3)) * 8;   // swizzled Ks k-slot

    for (int it = 0; it < NIT; ++it) {
        const int i0 = (wave * NIT + it) * 16;
        const f16x8 qf = *(const f16x8*)(qg + (size_t)(i0 + col) * CH + quad * 8);
        f32x4 st[JT];
#pragma unroll
        for (int mt = 0; mt < JT; ++mt) {
            f16x8 kf = *(const f16x8*)(Ks + (mt * 16 + col) * CH + kq8);
            st[mt] = __builtin_amdgcn_mfma_f32_16x16x32_f16(kf, qf, (f32x4){0.f, 0.f, 0.f, 0.f}, 0, 0, 0);
        }
        float sum = 0.f;
#pragma unroll
        for (int mt = 0; mt < JT; ++mt)
#pragma unroll
            for (int r = 0; r < 4; ++r) {
                st[mt][r] = __expf(st[mt][r]);
                sum += st[mt][r];
            }
        sum += __shfl_xor(sum, 16, 64);
        sum += __shfl_xor(sum, 32, 64);
        const float inv = 1.f / sum;
#pragma unroll
        for (int mt = 0; mt < JT; ++mt) {
            union { uint2 u; f16_t h4[4]; } w;
            w.h4[0] = (f16_t)(st[mt][0] * inv);
            w.h4[1] = (f16_t)(st[mt][1] * inv);
            w.h4[2] = (f16_t)(st[mt][2] * inv);
            w.h4[3] = (f16_t)(st[mt][3] * inv);
            *(uint2*)(mypb + col * PST + mt * 16 + quad * 4) = w.u;
        }
        WAVE_LDS_FENCE();   // per-wave pb: wave-local drain suffices

        // PV: 2 accumulation chains per output row-pair to break MFMA latency
        f32x4 o0a = {0.f, 0.f, 0.f, 0.f}, o0b = {0.f, 0.f, 0.f, 0.f};
        f32x4 o1a = {0.f, 0.f, 0.f, 0.f}, o1b = {0.f, 0.f, 0.f, 0.f};
#pragma unroll
        for (int ks = 0; ks < SEQ / 32; ks += 2) {
            f16x8 pf0 = *(const f16x8*)(mypb + col * PST + ks * 32 + quad * 8);
            f16x8 pf1 = *(const f16x8*)(mypb + col * PST + (ks + 1) * 32 + quad * 8);
            f16x8 va0 = *(const f16x8*)(Vs + col * VST + ks * 32 + quad * 8);
            f16x8 va1 = *(const f16x8*)(Vs + col * VST + (ks + 1) * 32 + quad * 8);
            f16x8 vb0 = *(const f16x8*)(Vs + (16 + col) * VST + ks * 32 + quad * 8);
            f16x8 vb1 = *(const f16x8*)(Vs + (16 + col) * VST + (ks + 1) * 32 + quad * 8);
            o0a = __builtin_amdgcn_mfma_f32_16x16x32_f16(va0, pf0, o0a, 0, 0, 0);
            o0b = __builtin_amdgcn_mfma_f32_16x16x32_f16(va1, pf1, o0b, 0, 0, 0);
            o1a = __builtin_amdgcn_mfma_f32_16x16x32_f16(vb0, pf0, o1a, 0, 0, 0);
            o1b = __builtin_amdgcn_mfma_f32_16x16x32_f16(vb1, pf1, o1b, 0, 0, 0);
        }
        const f32x4 ot0 = o0a + o0b;
        const f32x4 ot1 = o1a + o1b;

        const size_t pos = pbase + i0 + col;
        if constexpr (XT16) {
            const f16_t* Xh = (const f16_t*)Xv_;
            const f16x4 xa = *(const f16x4*)(Xh + pos * DCH + h * CH + quad * 4);
            const f16x4 xb = *(const f16x4*)(Xh + pos * DCH + h * CH + 16 + quad * 4);
#pragma unroll
            for (int r = 0; r < 4; ++r) {
                R[(size_t)(h * CH + quad * 4 + r) * NPOS + pos]      = (float)xa[r] + ot0[r];
                R[(size_t)(h * CH + 16 + quad * 4 + r) * NPOS + pos] = (float)xb[r] + ot1[r];
            }
        } else {
            const float* Xf = (const float*)Xv_;
#pragma unroll
            for (int r = 0; r < 4; ++r) {
                const size_t c0r = (size_t)(h * CH + quad * 4 + r) * NPOS + pos;
                const size_t c1r = (size_t)(h * CH + 16 + quad * 4 + r) * NPOS + pos;
                R[c0r] = Xf[c0r] + ot0[r];
                R[c1r] = Xf[c1r] + ot1[r];
            }
        }
    }
}

// ---------------------------------------------------------------------------
// LN stats: mu[p], rs[p] over the 384 channels of A[d][p].
// ---------------------------------------------------------------------------
__global__ __launch_bounds__(256) void ln_stats(const float* __restrict__ A,
                                                float* __restrict__ mu,
                                                float* __restrict__ rs) {
    __shared__ float ssum[4][64], ssq[4][64];
    const int i = threadIdx.x & 63;
    const int g = threadIdx.x >> 6;
    const int p = blockIdx.x * 64 + i;
    float sum = 0.f, sq = 0.f;
    const float* ap = A + (size_t)(g * 96) * NPOS + p;
#pragma unroll 4
    for (int d = 0; d < 96; ++d) {
        float v = ap[(size_t)d * NPOS];
        sum += v;
        sq += v * v;
    }
    ssum[g][i] = sum;
    ssq[g][i] = sq;
    __syncthreads();
    if (g == 0) {
        float s = ssum[0][i] + ssum[1][i] + ssum[2][i] + ssum[3][i];
        float q = ssq[0][i] + ssq[1][i] + ssq[2][i] + ssq[3][i];
        float m = s * (1.f / DCH);
        float var = q * (1.f / DCH) - m * m;
        mu[p] = m;
        rs[p] = rsqrtf(var + 1e-5f);
    }
}

// ---------------------------------------------------------------------------
// Fused LN-apply + transpose + fp16: A fp32 [d][s*LL+l] -> Xp fp16
// [(l*SS+s)][d].
// ---------------------------------------------------------------------------
__global__ __launch_bounds__(256) void norm_xT(
        const float* __restrict__ A, const float* __restrict__ mu,
        const float* __restrict__ rs, const float* __restrict__ w,
        const float* __restrict__ b, f16_t* __restrict__ Xp) {
    __shared__ float tile[64][65];
    const int l0 = (blockIdx.x & 3) * 64;          // LL/64 = 4
    const int s  = (blockIdx.x >> 2) & (SS - 1);   // 128
    const int k0 = (blockIdx.x >> 9) * 64;         // DCH/64 = 6
    const int tx = threadIdx.x & 63, ty = threadIdx.x >> 6;  // ty 0..3
    const int pos0 = s * LL + l0;
#pragma unroll
    for (int i = 0; i < 16; ++i) {
        const int d = k0 + ty * 16 + i;
        float v = A[(size_t)d * NPOS + pos0 + tx];
        tile[ty * 16 + i][tx] = (v - mu[pos0 + tx]) * rs[pos0 + tx] * w[d] + b[d];
    }
    __syncthreads();
    const int pr = threadIdx.x >> 2;   // l-offset 0..63
    const int cg = threadIdx.x & 3;    // 16-d group
    union { uint4 v[2]; unsigned int u[8]; } res;
#pragma unroll
    for (int j = 0; j < 8; ++j) {
        unsigned short lo = __builtin_bit_cast(unsigned short, (f16_t)tile[cg * 16 + 2 * j][pr]);
        unsigned short hi = __builtin_bit_cast(unsigned short, (f16_t)tile[cg * 16 + 2 * j + 1][pr]);
        res.u[j] = (unsigned)lo | ((unsigned)hi << 16);
    }
    uint4* dst = (uint4*)&Xp[(size_t)((l0 + pr) * SS + s) * DCH + k0 + cg * 16];
    dst[0] = res.v[0];
    dst[1] = res.v[1];
}

// ---------------------------------------------------------------------------
// Final: normalize + per-channel transpose back to original domain.
// ---------------------------------------------------------------------------
__global__ __launch_bounds__(256) void norm_transpose(
        const float* __restrict__ in, const float* __restrict__ mu,
        const float* __restrict__ rs, const float* __restrict__ w,
        const float* __restrict__ b, float* __restrict__ out, int Rr, int Cc) {
    __shared__ float tile[32][33];
    const int ntc = Cc >> 5, ntr = Rr >> 5;
    int tc = blockIdx.x % ntc;
    int tr = (blockIdx.x / ntc) % ntr;
    int d = blockIdx.x / (ntc * ntr);
    int tx = threadIdx.x & 31, ty = threadIdx.x >> 5;  // ty 0..7
    const float* ip = in + (size_t)d * Rr * Cc;
    float* op = out + (size_t)d * Rr * Cc;
    const float wd = w[d], bd = b[d];
#pragma unroll
    for (int i = 0; i < 32; i += 8) {
        const int r = tr * 32 + ty + i;
        const int c = tc * 32 + tx;
        const int pos = r * Cc + c;
        float v = ip[(size_t)r * Cc + c];
        tile[ty + i][tx] = (v - mu[pos]) * rs[pos] * wd + bd;
    }
    __syncthreads();
#pragma unroll
    for (int i = 0; i < 32; i += 8)
        op[(size_t)(tc * 32 + ty + i) * Rr + tr * 32 + tx] = tile[tx][ty + i];
}

extern "C" void kernel_launch(void* const* d_in, const int* in_sizes, int n_in,
                              void* d_out, int out_size, void* d_ws, size_t ws_size,
                              hipStream_t stream) {
    const float* x     = (const float*)d_in[0];
    const float* row_w = (const float*)d_in[1];
    const float* row_b = (const float*)d_in[2];
    const float* col_w = (const float*)d_in[3];
    const float* col_b = (const float*)d_in[4];
    const float* ln1_w = (const float*)d_in[5];
    const float* ln1_b = (const float*)d_in[6];
    const float* ln2_w = (const float*)d_in[7];
    const float* ln2_b = (const float*)d_in[8];
    float* out = (float*)d_out;

    char* ws = (char*)d_ws;
    const size_t ysz = (size_t)NH * NPOS * CH * 2;   // 25.2 MB (== DCH*NPOS*2)
    const size_t abytes = (size_t)DCH * NPOS * 4;    // 50.3 MB
    f16_t* Yq = (f16_t*)ws;
    f16_t* Yk = (f16_t*)(ws + ysz);
    f16_t* Yv = (f16_t*)(ws + 2 * ysz);
    float* A  = (float*)(ws + 3 * ysz);
    f16_t* Xp = (f16_t*)(ws + 3 * ysz + abytes);
    f16_t* Wh = (f16_t*)(ws + 3 * ysz + abytes + ysz);
    float* MU = (float*)(ws + 3 * ysz + abytes + ysz + (1 << 21));
    float* RS = MU + NPOS;

    dim3 ggrid(THREE_D / 128, NPOS / 256);   // x = o-tile (9), y = p-tile (128)
    const int wn4 = THREE_D * DCH / 4;
    dim3 cgrid(NPOS / 64, DCH / 64);

    // ---- stage 1: row attention (attend over L within each row s) ----
    conv_w<<<(wn4 + 255) / 256, 256, 0, stream>>>(row_w, Wh, wn4);
    conv_xT<<<cgrid, 256, 0, stream>>>(x, Xp);
    qkv_gemm_f16<<<ggrid, 512, 0, stream>>>(Wh, row_b, Xp, Yq, Yk, Yv);
    mfma_attn<LL, false><<<NH * SS, 256, 0, stream>>>(Yq, Yk, Yv, x, A);  // A = x + row_out
    ln_stats<<<NPOS / 64, 256, 0, stream>>>(A, MU, RS);
    norm_xT<<<(DCH / 64) * SS * (LL / 64), 256, 0, stream>>>(A, MU, RS, ln1_w, ln1_b, Xp);

    // ---- stage 2: column attention (attend over S within each column l) ----
    conv_w<<<(wn4 + 255) / 256, 256, 0, stream>>>(col_w, Wh, wn4);
    qkv_gemm_f16<<<ggrid, 512, 0, stream>>>(Wh, col_b, Xp, Yq, Yk, Yv);
    mfma_attn<SS, true><<<NH * LL, 256, 0, stream>>>(Yq, Yk, Yv, Xp, A);  // A = out1 + col_out
    ln_stats<<<NPOS / 64, 256, 0, stream>>>(A, MU, RS);
    norm_transpose<<<DCH * (LL / 32) * (SS / 32), 256, 0, stream>>>(
        A, MU, RS, ln2_w, ln2_b, out, LL, SS);
}

// Round 5
// 320.665 us; speedup vs baseline: 1.0972x; 1.0690x over previous
//
#include <hip/hip_runtime.h>
#include <math.h>

#define DCH 384
#define NH 12
#define CH 32
#define SS 128
#define LL 256
#define NPOS 32768        // SS*LL
#define THREE_D 1152

typedef _Float16 f16_t;
typedef _Float16 f16x4 __attribute__((ext_vector_type(4)));
typedef _Float16 f16x8 __attribute__((ext_vector_type(8)));
typedef float f32x4 __attribute__((ext_vector_type(4)));

// async global->LDS, 16B per lane.
#define GLD16(gptr, lptr) __builtin_amdgcn_global_load_lds( \
    (const __attribute__((address_space(1))) unsigned int*)(gptr), \
    (__attribute__((address_space(3))) unsigned int*)(lptr), 16, 0, 0)

#define WAVE_LDS_FENCE() __asm__ volatile("s_waitcnt lgkmcnt(0)" ::: "memory")

// ---------------------------------------------------------------------------
// fp32 -> fp16 elementwise (weights, layout preserved). n4 = count/4.
// ---------------------------------------------------------------------------
__global__ __launch_bounds__(256) void conv_w(const float* __restrict__ in,
                                              f16_t* __restrict__ out, int n4) {
    int i = blockIdx.x * 256 + threadIdx.x;
    if (i < n4) {
        float4 v = ((const float4*)in)[i];
        unsigned short u0 = __builtin_bit_cast(unsigned short, (f16_t)v.x);
        unsigned short u1 = __builtin_bit_cast(unsigned short, (f16_t)v.y);
        unsigned short u2 = __builtin_bit_cast(unsigned short, (f16_t)v.z);
        unsigned short u3 = __builtin_bit_cast(unsigned short, (f16_t)v.w);
        uint2 r;
        r.x = (unsigned)u0 | ((unsigned)u1 << 16);
        r.y = (unsigned)u2 | ((unsigned)u3 << 16);
        ((uint2*)out)[i] = r;
    }
}

// ---------------------------------------------------------------------------
// zero 2*NPOS floats (SUM/SQ accumulators). grid 64 x 256, float4.
// ---------------------------------------------------------------------------
__global__ __launch_bounds__(256) void zero_stats(float* __restrict__ p) {
    ((float4*)p)[blockIdx.x * 256 + threadIdx.x] = (float4){0.f, 0.f, 0.f, 0.f};
}

// ---------------------------------------------------------------------------
// fp32 [DCH][NPOS] -> fp16 [NPOS][DCH]  (transpose + convert, 64x64 tiles)
// ---------------------------------------------------------------------------
__global__ __launch_bounds__(256) void conv_xT(const float* __restrict__ in,
                                               f16_t* __restrict__ outp) {
    __shared__ float tile[64][65];
    const int p0 = blockIdx.x * 64;
    const int k0 = blockIdx.y * 64;
    const int tx = threadIdx.x & 63, ty = threadIdx.x >> 6;  // ty 0..3
#pragma unroll
    for (int i = 0; i < 16; ++i)
        tile[ty * 16 + i][tx] = in[(size_t)(k0 + ty * 16 + i) * NPOS + p0 + tx];
    __syncthreads();
    const int pr = threadIdx.x >> 2;   // 0..63 output row (p)
    const int cg = threadIdx.x & 3;    // 16-col group (k)
    union { uint4 v[2]; unsigned int u[8]; } res;
#pragma unroll
    for (int j = 0; j < 8; ++j) {
        unsigned short lo = __builtin_bit_cast(unsigned short, (f16_t)tile[cg * 16 + 2 * j][pr]);
        unsigned short hi = __builtin_bit_cast(unsigned short, (f16_t)tile[cg * 16 + 2 * j + 1][pr]);
        res.u[j] = (unsigned)lo | ((unsigned)hi << 16);
    }
    uint4* dst = (uint4*)&outp[(size_t)(p0 + pr) * DCH + k0 + cg * 16];
    dst[0] = res.v[0];
    dst[1] = res.v[1];
}

// ---------------------------------------------------------------------------
// fp16 MFMA GEMM (R4 structure: whole A panel in LDS once, barrier-free
// K-loop, B streamed global->reg depth-2, bijective XCD swizzle).
// ---------------------------------------------------------------------------
__global__ __launch_bounds__(512) void qkv_gemm_f16(
        const f16_t* __restrict__ Wh,    // [THREE_D][DCH]
        const float* __restrict__ bias,  // [THREE_D]
        const f16_t* __restrict__ Xp,    // [NPOS][DCH]
        f16_t* __restrict__ Yq, f16_t* __restrict__ Yk, f16_t* __restrict__ Yv)
{
    __shared__ f16_t sha[128 * 384];   // 96 KB; [row][slot^key] 16B slots
    const int tid  = threadIdx.x;
    const int lane = tid & 63;
    const int wave = tid >> 6;         // 0..7

    // Bijective XCD swizzle: nwg = 9*128 = 1152 = 8 * 144.
    const int hwid = blockIdx.y * 9 + blockIdx.x;      // x fastest in dispatch
    const int nid  = (hwid & 7) * 144 + (hwid >> 3);
    const int ot   = nid % 9;                           // 0..8
    const int pt   = nid / 9;                           // 0..127
    const int o0 = ot * 128;
    const int p0 = pt * 256;

    const int mrow = lane & 15;
    const int kgq  = lane >> 4;        // k-quad 0..3

    // ---- stage whole A panel (128 rows x 48 slots of 16B), once ----
#pragma unroll
    for (int j = 0; j < 12; ++j) {
        const int ibase = (wave * 12 + j) * 64;   // wave-uniform slot base
        const int i = ibase + lane;
        const int row = i / 48;
        const int s = i - row * 48;
        const int g = s ^ (row & 7);
        GLD16(Wh + (size_t)(o0 + row) * DCH + g * 8, sha + (size_t)ibase * 8);
    }

    const f16_t* bp0 = Xp + (size_t)(p0 + wave * 32 + mrow) * DCH + kgq * 8;
    const f16_t* bp1 = bp0 + (size_t)16 * DCH;

    f32x4 acc[8][2] = {};
    f16x8 breg[3][2];

    breg[0][0] = *(const f16x8*)(bp0);
    breg[0][1] = *(const f16x8*)(bp1);
    breg[1][0] = *(const f16x8*)(bp0 + 32);
    breg[1][1] = *(const f16x8*)(bp1 + 32);

    __syncthreads();   // the ONLY barrier: A panel visible to all waves

    const int key = mrow & 7;
    constexpr int NK = DCH / 32;       // 12
#pragma unroll
    for (int t = 0; t < NK; ++t) {
        if (t + 2 < NK) {
            breg[(t + 2) % 3][0] = *(const f16x8*)(bp0 + (t + 2) * 32);
            breg[(t + 2) % 3][1] = *(const f16x8*)(bp1 + (t + 2) * 32);
        }
        const int soff = ((t * 4 + kgq) ^ key) * 8;   // swizzled slot offset
#pragma unroll
        for (int mi = 0; mi < 8; ++mi) {
            const f16x8 a = *(const f16x8*)(sha + (size_t)(mi * 16 + mrow) * DCH + soff);
            acc[mi][0] = __builtin_amdgcn_mfma_f32_16x16x32_f16(
                a, breg[t % 3][0], acc[mi][0], 0, 0, 0);
            acc[mi][1] = __builtin_amdgcn_mfma_f32_16x16x32_f16(
                a, breg[t % 3][1], acc[mi][1], 0, 0, 0);
        }
    }

    // C/D layout: col = lane&15 (p), row = (lane>>4)*4 + r (o)
    const int col = lane & 15;
    const int rq4 = (lane >> 4) * 4;
    const int qkv = ot / 3;     // 0=q 1=k 2=v
    const int grp = ot % 3;     // 128-block within the qkv group

    if (qkv < 2) {
        f16_t* Yt = (qkv == 0) ? Yq : Yk;
#pragma unroll
        for (int mi = 0; mi < 8; ++mi) {
            const int h  = grp * 4 + (mi >> 1);
            const int cb = (mi & 1) * 16 + rq4;               // c base; +r consecutive
            const int ob = o0 + mi * 16 + rq4;                // bias base
            const float b0 = bias[ob], b1 = bias[ob + 1];
            const float b2 = bias[ob + 2], b3 = bias[ob + 3];
#pragma unroll
            for (int ni = 0; ni < 2; ++ni) {
                const int p = p0 + wave * 32 + ni * 16 + col;
                union { uint2 u; f16_t h4[4]; } w;
                w.h4[0] = (f16_t)(acc[mi][ni][0] + b0);
                w.h4[1] = (f16_t)(acc[mi][ni][1] + b1);
                w.h4[2] = (f16_t)(acc[mi][ni][2] + b2);
                w.h4[3] = (f16_t)(acc[mi][ni][3] + b3);
                *(uint2*)(Yt + ((size_t)h * NPOS + p) * CH + cb) = w.u;
            }
        }
    } else {
#pragma unroll
        for (int mi = 0; mi < 8; ++mi) {
#pragma unroll
            for (int r = 0; r < 4; ++r) {
                const int cg = grp * 128 + mi * 16 + rq4 + r;  // 0..383
                const float br = bias[768 + cg];
#pragma unroll
                for (int ni = 0; ni < 2; ++ni) {
                    const int p = p0 + wave * 32 + ni * 16 + col;
                    Yv[(size_t)cg * NPOS + p] = (f16_t)(acc[mi][ni][r] + br);
                }
            }
        }
    }
}

// ---------------------------------------------------------------------------
// MFMA axial attention, LDS-staged K/V.
// R5: A output is now fp16 (halves write + downstream read traffic), and the
//     epilogue computes per-position partial LN stats (sum, sumsq over this
//     head's 32 channels) and atomicAdds into SUM/SQ (device-scope; Guideline
//     12: 2 shuffles + 2 atomics per position per block). ln_stats kernel
//     eliminated.
// ---------------------------------------------------------------------------
template <int SEQ, bool XT16>
__global__ __launch_bounds__(256) void mfma_attn(
        const f16_t* __restrict__ Yq, const f16_t* __restrict__ Yk,
        const f16_t* __restrict__ Yv, const void* __restrict__ Xv_,
        f16_t* __restrict__ R, float* __restrict__ SUM, float* __restrict__ SQ)
{
    constexpr int JT  = SEQ / 16;    // j-tiles
    constexpr int NIT = SEQ / 64;    // i-tiles per wave
    constexpr int PST = SEQ + 8;     // padded P row stride (fp16 units)
    constexpr int VST = SEQ + 8;     // padded V row stride
    __shared__ f16_t Ks[SEQ * CH];       // [pos][ch-swz]
    __shared__ f16_t Vs[CH * VST];       // [ch][pos]
    __shared__ f16_t pb[4][16 * PST];
    const int tid  = threadIdx.x;
    const int lane = tid & 63;
    const int wave = tid >> 6;
    const int col = lane & 15, quad = lane >> 4;
    const int h = blockIdx.x % NH;
    const size_t pbase = (size_t)(blockIdx.x / NH) * SEQ;

    const f16_t* qg = Yq + ((size_t)h * NPOS + pbase) * CH;
    const f16_t* kg = Yk + ((size_t)h * NPOS + pbase) * CH;
    const f16_t* vg = Yv + (size_t)h * CH * NPOS + pbase;
    f16_t* mypb = pb[wave];

    // ---- stage K (async, linear dest; source k-group pre-swizzled) ----
    {
        const int ksw = (lane & 3) ^ ((lane >> 3) & 3);
        const int lrow32 = (lane >> 2) * 32;
#pragma unroll
        for (int i = 0; i < SEQ / 64; ++i) {
            const int off = (wave * (SEQ / 64) + i) * 512;  // f16 units
            GLD16(kg + off + lrow32 + ksw * 8, Ks + off);
        }
    }
    // ---- stage V^T (coalesced float4, padded rows) ----
    {
        constexpr int CPR = SEQ / 8;
        const int vch = tid % CPR;
        const int vr0 = tid / CPR;
#pragma unroll
        for (int r = vr0; r < CH; r += 256 / CPR)
            *(float4*)(Vs + r * VST + vch * 8) =
                *(const float4*)(vg + (size_t)r * NPOS + vch * 8);
    }
    __syncthreads();

    const int kq8 = (quad ^ ((col >> 1) & 3)) * 8;   // swizzled Ks k-slot

    for (int it = 0; it < NIT; ++it) {
        const int i0 = (wave * NIT + it) * 16;
        const f16x8 qf = *(const f16x8*)(qg + (size_t)(i0 + col) * CH + quad * 8);
        f32x4 st[JT];
#pragma unroll
        for (int mt = 0; mt < JT; ++mt) {
            f16x8 kf = *(const f16x8*)(Ks + (mt * 16 + col) * CH + kq8);
            st[mt] = __builtin_amdgcn_mfma_f32_16x16x32_f16(kf, qf, (f32x4){0.f, 0.f, 0.f, 0.f}, 0, 0, 0);
        }
        float sum = 0.f;
#pragma unroll
        for (int mt = 0; mt < JT; ++mt)
#pragma unroll
            for (int r = 0; r < 4; ++r) {
                st[mt][r] = __expf(st[mt][r]);
                sum += st[mt][r];
            }
        sum += __shfl_xor(sum, 16, 64);
        sum += __shfl_xor(sum, 32, 64);
        const float inv = 1.f / sum;
#pragma unroll
        for (int mt = 0; mt < JT; ++mt) {
            union { uint2 u; f16_t h4[4]; } w;
            w.h4[0] = (f16_t)(st[mt][0] * inv);
            w.h4[1] = (f16_t)(st[mt][1] * inv);
            w.h4[2] = (f16_t)(st[mt][2] * inv);
            w.h4[3] = (f16_t)(st[mt][3] * inv);
            *(uint2*)(mypb + col * PST + mt * 16 + quad * 4) = w.u;
        }
        WAVE_LDS_FENCE();

        f32x4 o0a = {0.f, 0.f, 0.f, 0.f}, o0b = {0.f, 0.f, 0.f, 0.f};
        f32x4 o1a = {0.f, 0.f, 0.f, 0.f}, o1b = {0.f, 0.f, 0.f, 0.f};
#pragma unroll
        for (int ks = 0; ks < SEQ / 32; ks += 2) {
            f16x8 pf0 = *(const f16x8*)(mypb + col * PST + ks * 32 + quad * 8);
            f16x8 pf1 = *(const f16x8*)(mypb + col * PST + (ks + 1) * 32 + quad * 8);
            f16x8 va0 = *(const f16x8*)(Vs + col * VST + ks * 32 + quad * 8);
            f16x8 va1 = *(const f16x8*)(Vs + col * VST + (ks + 1) * 32 + quad * 8);
            f16x8 vb0 = *(const f16x8*)(Vs + (16 + col) * VST + ks * 32 + quad * 8);
            f16x8 vb1 = *(const f16x8*)(Vs + (16 + col) * VST + (ks + 1) * 32 + quad * 8);
            o0a = __builtin_amdgcn_mfma_f32_16x16x32_f16(va0, pf0, o0a, 0, 0, 0);
            o0b = __builtin_amdgcn_mfma_f32_16x16x32_f16(va1, pf1, o0b, 0, 0, 0);
            o1a = __builtin_amdgcn_mfma_f32_16x16x32_f16(vb0, pf0, o1a, 0, 0, 0);
            o1b = __builtin_amdgcn_mfma_f32_16x16x32_f16(vb1, pf1, o1b, 0, 0, 0);
        }
        const f32x4 ot0 = o0a + o0b;
        const f32x4 ot1 = o1a + o1b;

        const size_t pos = pbase + i0 + col;
        float a0[4], a1[4];
        if constexpr (XT16) {
            const f16_t* Xh = (const f16_t*)Xv_;
            const f16x4 xa = *(const f16x4*)(Xh + pos * DCH + h * CH + quad * 4);
            const f16x4 xb = *(const f16x4*)(Xh + pos * DCH + h * CH + 16 + quad * 4);
#pragma unroll
            for (int r = 0; r < 4; ++r) {
                a0[r] = (float)xa[r] + ot0[r];
                a1[r] = (float)xb[r] + ot1[r];
            }
        } else {
            const float* Xf = (const float*)Xv_;
#pragma unroll
            for (int r = 0; r < 4; ++r) {
                a0[r] = Xf[(size_t)(h * CH + quad * 4 + r) * NPOS + pos] + ot0[r];
                a1[r] = Xf[(size_t)(h * CH + 16 + quad * 4 + r) * NPOS + pos] + ot1[r];
            }
        }
        float psum = 0.f, psq = 0.f;
#pragma unroll
        for (int r = 0; r < 4; ++r) {
            R[(size_t)(h * CH + quad * 4 + r) * NPOS + pos]      = (f16_t)a0[r];
            R[(size_t)(h * CH + 16 + quad * 4 + r) * NPOS + pos] = (f16_t)a1[r];
            psum += a0[r] + a1[r];
            psq  += a0[r] * a0[r] + a1[r] * a1[r];
        }
        // cross-quad reduce (col fixed): full 32-channel partial for this head
        psum += __shfl_xor(psum, 16, 64);
        psum += __shfl_xor(psum, 32, 64);
        psq  += __shfl_xor(psq, 16, 64);
        psq  += __shfl_xor(psq, 32, 64);
        if (quad == 0) {
            atomicAdd(&SUM[pos], psum);
            atomicAdd(&SQ[pos], psq);
        }
    }
}

// ---------------------------------------------------------------------------
// Fused LN-apply + transpose + fp16: A fp16 [d][s*LL+l] -> Xp fp16
// [(l*SS+s)][d]. mu/rs computed inline from fused SUM/SQ.
// ---------------------------------------------------------------------------
__global__ __launch_bounds__(256) void norm_xT(
        const f16_t* __restrict__ A, const float* __restrict__ SUM,
        const float* __restrict__ SQ, const float* __restrict__ w,
        const float* __restrict__ b, f16_t* __restrict__ Xp) {
    __shared__ float tile[64][65];
    const int l0 = (blockIdx.x & 3) * 64;          // LL/64 = 4
    const int s  = (blockIdx.x >> 2) & (SS - 1);   // 128
    const int k0 = (blockIdx.x >> 9) * 64;         // DCH/64 = 6
    const int tx = threadIdx.x & 63, ty = threadIdx.x >> 6;  // ty 0..3
    const int pos0 = s * LL + l0;
    const float m  = SUM[pos0 + tx] * (1.f / DCH);
    const float rs = rsqrtf(SQ[pos0 + tx] * (1.f / DCH) - m * m + 1e-5f);
#pragma unroll
    for (int i = 0; i < 16; ++i) {
        const int d = k0 + ty * 16 + i;
        float v = (float)A[(size_t)d * NPOS + pos0 + tx];
        tile[ty * 16 + i][tx] = (v - m) * rs * w[d] + b[d];
    }
    __syncthreads();
    const int pr = threadIdx.x >> 2;   // l-offset 0..63
    const int cg = threadIdx.x & 3;    // 16-d group
    union { uint4 v[2]; unsigned int u[8]; } res;
#pragma unroll
    for (int j = 0; j < 8; ++j) {
        unsigned short lo = __builtin_bit_cast(unsigned short, (f16_t)tile[cg * 16 + 2 * j][pr]);
        unsigned short hi = __builtin_bit_cast(unsigned short, (f16_t)tile[cg * 16 + 2 * j + 1][pr]);
        res.u[j] = (unsigned)lo | ((unsigned)hi << 16);
    }
    uint4* dst = (uint4*)&Xp[(size_t)((l0 + pr) * SS + s) * DCH + k0 + cg * 16];
    dst[0] = res.v[0];
    dst[1] = res.v[1];
}

// ---------------------------------------------------------------------------
// Final: normalize (inline mu/rs from SUM/SQ) + per-channel transpose.
// in is fp16 A [d][LL*SS-domain]; out fp32.
// ---------------------------------------------------------------------------
__global__ __launch_bounds__(256) void norm_transpose(
        const f16_t* __restrict__ in, const float* __restrict__ SUM,
        const float* __restrict__ SQ, const float* __restrict__ w,
        const float* __restrict__ b, float* __restrict__ out, int Rr, int Cc) {
    __shared__ float tile[32][33];
    const int ntc = Cc >> 5, ntr = Rr >> 5;
    int tc = blockIdx.x % ntc;
    int tr = (blockIdx.x / ntc) % ntr;
    int d = blockIdx.x / (ntc * ntr);
    int tx = threadIdx.x & 31, ty = threadIdx.x >> 5;  // ty 0..7
    const f16_t* ip = in + (size_t)d * Rr * Cc;
    float* op = out + (size_t)d * Rr * Cc;
    const float wd = w[d], bd = b[d];
#pragma unroll
    for (int i = 0; i < 32; i += 8) {
        const int r = tr * 32 + ty + i;
        const int c = tc * 32 + tx;
        const int pos = r * Cc + c;
        const float m  = SUM[pos] * (1.f / DCH);
        const float rs = rsqrtf(SQ[pos] * (1.f / DCH) - m * m + 1e-5f);
        float v = (float)ip[(size_t)r * Cc + c];
        tile[ty + i][tx] = (v - m) * rs * wd + bd;
    }
    __syncthreads();
#pragma unroll
    for (int i = 0; i < 32; i += 8)
        op[(size_t)(tc * 32 + ty + i) * Rr + tr * 32 + tx] = tile[tx][ty + i];
}

extern "C" void kernel_launch(void* const* d_in, const int* in_sizes, int n_in,
                              void* d_out, int out_size, void* d_ws, size_t ws_size,
                              hipStream_t stream) {
    const float* x     = (const float*)d_in[0];
    const float* row_w = (const float*)d_in[1];
    const float* row_b = (const float*)d_in[2];
    const float* col_w = (const float*)d_in[3];
    const float* col_b = (const float*)d_in[4];
    const float* ln1_w = (const float*)d_in[5];
    const float* ln1_b = (const float*)d_in[6];
    const float* ln2_w = (const float*)d_in[7];
    const float* ln2_b = (const float*)d_in[8];
    float* out = (float*)d_out;

    char* ws = (char*)d_ws;
    const size_t ysz = (size_t)NH * NPOS * CH * 2;   // 25.2 MB (== DCH*NPOS*2)
    const size_t abytes = (size_t)DCH * NPOS * 4;    // region kept (A uses half)
    f16_t* Yq = (f16_t*)ws;
    f16_t* Yk = (f16_t*)(ws + ysz);
    f16_t* Yv = (f16_t*)(ws + 2 * ysz);
    f16_t* A  = (f16_t*)(ws + 3 * ysz);              // fp16 now, 25.2 MB
    f16_t* Xp = (f16_t*)(ws + 3 * ysz + abytes);
    f16_t* Wh = (f16_t*)(ws + 3 * ysz + abytes + ysz);
    float* SUMB = (float*)(ws + 3 * ysz + abytes + ysz + (1 << 21));
    float* SQB  = SUMB + NPOS;

    dim3 ggrid(THREE_D / 128, NPOS / 256);   // x = o-tile (9), y = p-tile (128)
    const int wn4 = THREE_D * DCH / 4;
    dim3 cgrid(NPOS / 64, DCH / 64);

    // ---- stage 1: row attention (attend over L within each row s) ----
    conv_w<<<(wn4 + 255) / 256, 256, 0, stream>>>(row_w, Wh, wn4);
    conv_xT<<<cgrid, 256, 0, stream>>>(x, Xp);
    zero_stats<<<2 * NPOS / 1024, 256, 0, stream>>>(SUMB);
    qkv_gemm_f16<<<ggrid, 512, 0, stream>>>(Wh, row_b, Xp, Yq, Yk, Yv);
    mfma_attn<LL, false><<<NH * SS, 256, 0, stream>>>(Yq, Yk, Yv, x, A, SUMB, SQB);
    norm_xT<<<(DCH / 64) * SS * (LL / 64), 256, 0, stream>>>(A, SUMB, SQB, ln1_w, ln1_b, Xp);

    // ---- stage 2: column attention (attend over S within each column l) ----
    conv_w<<<(wn4 + 255) / 256, 256, 0, stream>>>(col_w, Wh, wn4);
    zero_stats<<<2 * NPOS / 1024, 256, 0, stream>>>(SUMB);
    qkv_gemm_f16<<<ggrid, 512, 0, stream>>>(Wh, col_b, Xp, Yq, Yk, Yv);
    mfma_attn<SS, true><<<NH * LL, 256, 0, stream>>>(Yq, Yk, Yv, Xp, A, SUMB, SQB);
    norm_transpose<<<DCH * (LL / 32) * (SS / 32), 256, 0, stream>>>(
        A, SUMB, SQB, ln2_w, ln2_b, out, LL, SS);
}